// Round 1
// baseline (236.626 us; speedup 1.0000x reference)
//
#include <hip/hip_runtime.h>
#include <hip/hip_bf16.h>

#define S_LEN 2048
#define D_DIM 1024
#define NB 4

typedef float f32x4 __attribute__((ext_vector_type(4)));
typedef short short8 __attribute__((ext_vector_type(8)));
typedef unsigned short us4 __attribute__((ext_vector_type(4)));
typedef unsigned int u32x4 __attribute__((ext_vector_type(4)));

using bf16 = __hip_bfloat16;

static __device__ __forceinline__ unsigned short f2bf(float f) {
  bf16 h = __float2bfloat16(f);
  return *reinterpret_cast<unsigned short*>(&h);
}

// ---------------- mask dtype probe: 0=int32, 1=uint8, 2=float32 ----------------
__global__ void detect_mask_kernel(const unsigned int* __restrict__ m, int* __restrict__ flag) {
  __shared__ int sh;
  if (threadIdx.x == 0) sh = 0;
  __syncthreads();
  int f = 0;
  for (int i = threadIdx.x; i < 4096; i += 256) {
    unsigned int w = m[i];
    if (w == 0x3f800000u) f |= 2;      // exactly 1.0f
    if (w & 0xFFFFFF00u) f |= 1;       // high bytes set -> not int32 {0,1}
  }
  if (f) atomicOr(&sh, f);
  __syncthreads();
  if (threadIdx.x == 0) *flag = (sh & 2) ? 2 : ((sh & 1) ? 1 : 0);
}

// ---------------- fused positional-encoding + LayerNorm -> bf16 ----------------
__global__ __launch_bounds__(256) void pe_ln_kernel(
    const float* __restrict__ x, const float* __restrict__ lnw,
    const float* __restrict__ lnb, bf16* __restrict__ out) {
  const int row = blockIdx.x;            // b*2048 + s
  const int s = row & (S_LEN - 1);
  const int tid = threadIdx.x;
  const float pos = (float)s;
  const float* base = x + (size_t)row * D_DIM;

  f32x4 v = *(const f32x4*)(base + tid * 4);
  float h[4];
#pragma unroll
  for (int r = 0; r < 4; ++r) {
    int d = tid * 4 + r;
    float dv = (float)d * (2.0f / 1024.0f);
    float freq = exp2f(dv * -13.287712379549449f);  // 10000^-dv
    float pe = pos * freq;
    float pv = (d & 1) ? cosf(pe) : sinf(pe);
    h[r] = pv + v[r];
  }
  float ss = h[0] + h[1] + h[2] + h[3];
#pragma unroll
  for (int o = 32; o >= 1; o >>= 1) ss += __shfl_xor(ss, o);
  __shared__ float red[8];
  const int wave = tid >> 6, lane = tid & 63;
  if (lane == 0) red[wave] = ss;
  __syncthreads();
  const float mu = (red[0] + red[1] + red[2] + red[3]) * (1.0f / 1024.0f);
  float sq = 0.f;
#pragma unroll
  for (int r = 0; r < 4; ++r) { float d0 = h[r] - mu; sq += d0 * d0; }
#pragma unroll
  for (int o = 32; o >= 1; o >>= 1) sq += __shfl_xor(sq, o);
  if (lane == 0) red[4 + wave] = sq;
  __syncthreads();
  const float var = (red[4] + red[5] + red[6] + red[7]) * (1.0f / 1024.0f);
  const float inv = rsqrtf(var + 1e-5f);
  f32x4 wv = *(const f32x4*)(lnw + tid * 4);
  f32x4 bv = *(const f32x4*)(lnb + tid * 4);
  us4 o4;
#pragma unroll
  for (int r = 0; r < 4; ++r) o4[r] = f2bf((h[r] - mu) * inv * wv[r] + bv[r]);
  *(us4*)((unsigned short*)out + (size_t)row * D_DIM + tid * 4) = o4;
}

// ---------------- Wk fp32 [K][N] -> bf16 transposed [N][K] ----------------
__global__ __launch_bounds__(256) void wk_to_bf16t_kernel(const float* __restrict__ wk,
                                                          bf16* __restrict__ wt) {
  __shared__ float t[32][33];
  const int n0 = blockIdx.x * 32, k0 = blockIdx.y * 32;
  const int tx = threadIdx.x & 31, ty = threadIdx.x >> 5;  // ty 0..7
#pragma unroll
  for (int i = 0; i < 32; i += 8)
    t[ty + i][tx] = wk[(size_t)(k0 + ty + i) * 1024 + n0 + tx];
  __syncthreads();
#pragma unroll
  for (int i = 0; i < 32; i += 8)
    wt[(size_t)(n0 + ty + i) * 1024 + k0 + tx] = __float2bfloat16(t[tx][ty + i]);
}

// ---------------- generic bf16 GEMM, C = A[M][K] * B_t[N][K]^T ----------------
// EPI 0: + bias, write bf16 C (row-major) AND bf16 transposed copy (per batch of 2048 rows)
// EPI 1: * 1/32, masked-fill 1e-9, write fp32
// EPI 2: plain fp32 write
#define BM 128
#define BN 128
#define BK 32
#define LDP 40  // padded LDS K-stride (elements); 80B keeps 16B alignment, ~2-way banks

template <int EPI>
__global__ __launch_bounds__(256, 2) void gemm_bt_kernel(
    const bf16* __restrict__ A, int lda, long long A_bs,
    const bf16* __restrict__ B, int ldb, long long B_bs,
    int K,
    void* __restrict__ C, int ldc, long long C_bs,
    const float* __restrict__ bias, bf16* __restrict__ qkv_t,
    const void* __restrict__ mask, const int* __restrict__ flagp, int batch0) {
  __shared__ bf16 sA[BM * LDP];
  __shared__ bf16 sB[BN * LDP];

  const int tid = threadIdx.x;
  const int wave = tid >> 6, lane = tid & 63;
  const int wr = wave >> 1, wc = wave & 1;
  const int z = blockIdx.z;
  const int m0 = blockIdx.y * BM;
  const int n0 = blockIdx.x * BN;

  const bf16* Ab = A + (size_t)z * A_bs;
  const bf16* Bb = B + (size_t)z * B_bs;

  const int sr = tid >> 2;        // staging row 0..63
  const int sc = (tid & 3) * 8;   // staging col chunk

  int fmode = 0;
  if (EPI == 1) fmode = *flagp;

  f32x4 acc[4][4];
#pragma unroll
  for (int i = 0; i < 4; ++i)
#pragma unroll
    for (int j = 0; j < 4; ++j) acc[i][j] = (f32x4)(0.0f);

  const int lrow = lane & 15;
  const int kof = (lane >> 4) * 8;

  const bf16* pa0 = Ab + (size_t)(m0 + sr) * lda + sc;
  const bf16* pa1 = Ab + (size_t)(m0 + sr + 64) * lda + sc;
  const bf16* pb0 = Bb + (size_t)(n0 + sr) * ldb + sc;
  const bf16* pb1 = Bb + (size_t)(n0 + sr + 64) * ldb + sc;

  // prologue: load first tile into regs
  u32x4 a0 = *(const u32x4*)(pa0);
  u32x4 a1 = *(const u32x4*)(pa1);
  u32x4 b0 = *(const u32x4*)(pb0);
  u32x4 b1 = *(const u32x4*)(pb1);

  for (int k0 = 0; k0 < K; k0 += BK) {
    __syncthreads();  // previous iteration's frag reads done
    *(u32x4*)(sA + sr * LDP + sc) = a0;
    *(u32x4*)(sA + (sr + 64) * LDP + sc) = a1;
    *(u32x4*)(sB + sr * LDP + sc) = b0;
    *(u32x4*)(sB + (sr + 64) * LDP + sc) = b1;
    __syncthreads();
    if (k0 + BK < K) {  // prefetch next tile; latency hides under MFMA below
      a0 = *(const u32x4*)(pa0 + k0 + BK);
      a1 = *(const u32x4*)(pa1 + k0 + BK);
      b0 = *(const u32x4*)(pb0 + k0 + BK);
      b1 = *(const u32x4*)(pb1 + k0 + BK);
    }
    short8 af[4], bfr[4];
#pragma unroll
    for (int i = 0; i < 4; ++i) {
      af[i] = *(const short8*)(sA + (wr * 64 + i * 16 + lrow) * LDP + kof);
      bfr[i] = *(const short8*)(sB + (wc * 64 + i * 16 + lrow) * LDP + kof);
    }
#pragma unroll
    for (int i = 0; i < 4; ++i)
#pragma unroll
      for (int j = 0; j < 4; ++j)
        acc[i][j] = __builtin_amdgcn_mfma_f32_16x16x32_bf16(af[i], bfr[j], acc[i][j], 0, 0, 0);
  }

  // epilogue: C/D layout col = lane&15, row = (lane>>4)*4 + reg  [measured m89]
  const int r0 = (lane >> 4) * 4;
#pragma unroll
  for (int i = 0; i < 4; ++i) {
    const int rowl = m0 + wr * 64 + i * 16 + r0;
#pragma unroll
    for (int j = 0; j < 4; ++j) {
      const int col = n0 + wc * 64 + j * 16 + lrow;
      if (EPI == 0) {
        const float bv = bias[col];
        us4 pack;
#pragma unroll
        for (int r = 0; r < 4; ++r) {
          unsigned short hb = f2bf(acc[i][j][r] + bv);
          ((unsigned short*)C)[(size_t)(rowl + r) * ldc + col] = hb;
          pack[r] = hb;
        }
        const int bb = rowl >> 11, s = rowl & 2047;
        *(us4*)((unsigned short*)qkv_t + (size_t)bb * (1024ll * 2048) +
                (size_t)col * 2048 + s) = pack;
      } else if (EPI == 1) {
#pragma unroll
        for (int r = 0; r < 4; ++r) {
          const int row = rowl + r;
          float v = acc[i][j][r] * 0.03125f;
          const size_t midx = (size_t)(batch0 + z) * (2048ull * 2048) +
                              (size_t)row * 2048 + (size_t)col;
          int mv;
          if (fmode == 0) mv = ((const int*)mask)[midx];
          else if (fmode == 1) mv = (int)((const unsigned char*)mask)[midx];
          else mv = (((const float*)mask)[midx] != 0.0f);
          if (mv) v = 1e-9f;
          ((float*)C + (size_t)z * C_bs)[(size_t)row * ldc + col] = v;
        }
      } else {
#pragma unroll
        for (int r = 0; r < 4; ++r)
          ((float*)C + (size_t)z * C_bs)[(size_t)(rowl + r) * ldc + col] = acc[i][j][r];
      }
    }
  }
}

// ---------------- in-place row softmax: fp32 scores -> bf16 weights ----------------
__global__ __launch_bounds__(256) void softmax_kernel(float* __restrict__ scores) {
  const int row = blockIdx.x;
  float* base = scores + (size_t)row * 2048;
  const int tid = threadIdx.x;
  const int wave = tid >> 6, lane = tid & 63;
  f32x4 v0 = *(const f32x4*)(base + tid * 4);
  f32x4 v1 = *(const f32x4*)(base + 1024 + tid * 4);
  float m = v0[0];
#pragma unroll
  for (int r = 1; r < 4; ++r) m = fmaxf(m, v0[r]);
#pragma unroll
  for (int r = 0; r < 4; ++r) m = fmaxf(m, v1[r]);
#pragma unroll
  for (int o = 32; o >= 1; o >>= 1) m = fmaxf(m, __shfl_xor(m, o));
  __shared__ float red[8];
  if (lane == 0) red[wave] = m;
  __syncthreads();
  m = fmaxf(fmaxf(red[0], red[1]), fmaxf(red[2], red[3]));
  float sum = 0.f;
  float e0[4], e1[4];
#pragma unroll
  for (int r = 0; r < 4; ++r) { e0[r] = expf(v0[r] - m); sum += e0[r]; }
#pragma unroll
  for (int r = 0; r < 4; ++r) { e1[r] = expf(v1[r] - m); sum += e1[r]; }
#pragma unroll
  for (int o = 32; o >= 1; o >>= 1) sum += __shfl_xor(sum, o);
  if (lane == 0) red[4 + wave] = sum;
  __syncthreads();
  const float inv = 1.0f / (red[4] + red[5] + red[6] + red[7]);
  unsigned short* ob = (unsigned short*)base;   // in-place bf16 (reads all done pre-barrier)
  us4 p0, p1;
#pragma unroll
  for (int r = 0; r < 4; ++r) { p0[r] = f2bf(e0[r] * inv); p1[r] = f2bf(e1[r] * inv); }
  *(us4*)(ob + tid * 4) = p0;
  *(us4*)(ob + 1024 + tid * 4) = p1;
}

// ---------------- launcher ----------------
extern "C" void kernel_launch(void* const* d_in, const int* in_sizes, int n_in,
                              void* d_out, int out_size, void* d_ws, size_t ws_size,
                              hipStream_t stream) {
  const float* tensor = (const float*)d_in[0];
  const void* mask = d_in[1];
  const float* lnw = (const float*)d_in[2];
  const float* lnb = (const float*)d_in[3];
  const float* wk = (const float*)d_in[4];
  const float* bk = (const float*)d_in[5];
  float* out = (float*)d_out;

  // ws layout (bytes):
  //   0        : Wk_t bf16 [1024][1024]                  (2 MB)
  //   2 MB     : qkv_n bf16 [8192][1024]                 (16 MB)
  //   18 MB    : qkv_t bf16 [4][1024][2048]              (16 MB)
  //   34 MB    : x bf16 [8192][1024] (dead after gemm0)  (16 MB)
  //   34 MB    : scores fp32, 2 batches (aliases x)      (32 MB)
  //   66 MB    : mask-dtype flag                          (4 B)
  char* ws = (char*)d_ws;
  bf16* wkt = (bf16*)(ws);
  bf16* qkvn = (bf16*)(ws + (2ll << 20));
  bf16* qkvt = (bf16*)(ws + (18ll << 20));
  bf16* xbf = (bf16*)(ws + (34ll << 20));
  float* scores = (float*)(ws + (34ll << 20));
  int* flag = (int*)(ws + (66ll << 20));

  detect_mask_kernel<<<1, 256, 0, stream>>>((const unsigned int*)mask, flag);
  pe_ln_kernel<<<8192, 256, 0, stream>>>(tensor, lnw, lnb, xbf);
  wk_to_bf16t_kernel<<<dim3(32, 32), 256, 0, stream>>>(wk, wkt);

  // qkv = x @ Wk + bk   (M=8192, N=1024, K=1024) ; dual-write row-major + transposed
  gemm_bt_kernel<0><<<dim3(8, 64, 1), 256, 0, stream>>>(
      xbf, 1024, 0, wkt, 1024, 0, 1024,
      (void*)qkvn, 1024, 0, bk, qkvt, nullptr, nullptr, 0);

  for (int c = 0; c < 2; ++c) {
    // scores = qkv @ qkv^T / 32, mask-fill 1e-9  (per batch: M=N=2048, K=1024)
    gemm_bt_kernel<1><<<dim3(16, 16, 2), 256, 0, stream>>>(
        qkvn + (size_t)c * 2 * 2048 * 1024, 1024, 2048ll * 1024,
        qkvn + (size_t)c * 2 * 2048 * 1024, 1024, 2048ll * 1024, 1024,
        (void*)scores, 2048, 2048ll * 2048, nullptr, nullptr, mask, flag, c * 2);
    // softmax rows, in-place fp32 -> bf16 (row stride stays 4096 bf16 elements)
    softmax_kernel<<<4096, 256, 0, stream>>>(scores);
    // out = weights @ qkv  (per batch: M=2048, N=1024, K=2048)
    gemm_bt_kernel<2><<<dim3(8, 16, 2), 256, 0, stream>>>(
        (const bf16*)scores, 4096, 2048ll * 4096,
        qkvt + (size_t)c * 2 * 1024 * 2048, 2048, 1024ll * 2048, 2048,
        (void*)(out + (size_t)c * 2 * 2048 * 1024), 1024, 2048ll * 1024,
        nullptr, nullptr, nullptr, nullptr, 0);
  }
}

// Round 2
// 215.547 us; speedup vs baseline: 1.0978x; 1.0978x over previous
//
#include <hip/hip_runtime.h>
#include <hip/hip_bf16.h>

#define S_LEN 2048
#define D_DIM 1024

typedef float f32x4 __attribute__((ext_vector_type(4)));
typedef short short8 __attribute__((ext_vector_type(8)));
typedef unsigned short us4 __attribute__((ext_vector_type(4)));

using bf16 = __hip_bfloat16;

#define GLOBAL_AS(p) ((const __attribute__((address_space(1))) void*)(p))
#define LDS_AS(p) ((__attribute__((address_space(3))) void*)(p))

static __device__ __forceinline__ unsigned short f2bf(float f) {
  bf16 h = __float2bfloat16(f);
  return *reinterpret_cast<unsigned short*>(&h);
}

// ---------------- mask dtype probe: 0=int32, 1=uint8, 2=float32 ----------------
__global__ void detect_mask_kernel(const unsigned int* __restrict__ m, int* __restrict__ flag) {
  __shared__ int sh;
  if (threadIdx.x == 0) sh = 0;
  __syncthreads();
  int f = 0;
  for (int i = threadIdx.x; i < 4096; i += 256) {
    unsigned int w = m[i];
    if (w == 0x3f800000u) f |= 2;
    if (w & 0xFFFFFF00u) f |= 1;
  }
  if (f) atomicOr(&sh, f);
  __syncthreads();
  if (threadIdx.x == 0) *flag = (sh & 2) ? 2 : ((sh & 1) ? 1 : 0);
}

// ---------------- fused positional-encoding + LayerNorm -> bf16 ----------------
__global__ __launch_bounds__(256) void pe_ln_kernel(
    const float* __restrict__ x, const float* __restrict__ lnw,
    const float* __restrict__ lnb, bf16* __restrict__ out) {
  const int row = blockIdx.x;
  const int s = row & (S_LEN - 1);
  const int tid = threadIdx.x;
  const float pos = (float)s;
  const float* base = x + (size_t)row * D_DIM;

  f32x4 v = *(const f32x4*)(base + tid * 4);
  float h[4];
#pragma unroll
  for (int r = 0; r < 4; ++r) {
    int d = tid * 4 + r;
    float dv = (float)d * (2.0f / 1024.0f);
    float freq = exp2f(dv * -13.287712379549449f);
    float pe = pos * freq;
    float pv = (d & 1) ? cosf(pe) : sinf(pe);
    h[r] = pv + v[r];
  }
  float ss = h[0] + h[1] + h[2] + h[3];
#pragma unroll
  for (int o = 32; o >= 1; o >>= 1) ss += __shfl_xor(ss, o);
  __shared__ float red[8];
  const int wave = tid >> 6, lane = tid & 63;
  if (lane == 0) red[wave] = ss;
  __syncthreads();
  const float mu = (red[0] + red[1] + red[2] + red[3]) * (1.0f / 1024.0f);
  float sq = 0.f;
#pragma unroll
  for (int r = 0; r < 4; ++r) { float d0 = h[r] - mu; sq += d0 * d0; }
#pragma unroll
  for (int o = 32; o >= 1; o >>= 1) sq += __shfl_xor(sq, o);
  if (lane == 0) red[4 + wave] = sq;
  __syncthreads();
  const float var = (red[4] + red[5] + red[6] + red[7]) * (1.0f / 1024.0f);
  const float inv = rsqrtf(var + 1e-5f);
  f32x4 wv = *(const f32x4*)(lnw + tid * 4);
  f32x4 bv = *(const f32x4*)(lnb + tid * 4);
  us4 o4;
#pragma unroll
  for (int r = 0; r < 4; ++r) o4[r] = f2bf((h[r] - mu) * inv * wv[r] + bv[r]);
  *(us4*)((unsigned short*)out + (size_t)row * D_DIM + tid * 4) = o4;
}

// ---------------- Wk fp32 [K][N] -> bf16 transposed [N][K] ----------------
__global__ __launch_bounds__(256) void wk_to_bf16t_kernel(const float* __restrict__ wk,
                                                          bf16* __restrict__ wt) {
  __shared__ float t[32][33];
  const int n0 = blockIdx.x * 32, k0 = blockIdx.y * 32;
  const int tx = threadIdx.x & 31, ty = threadIdx.x >> 5;
#pragma unroll
  for (int i = 0; i < 32; i += 8)
    t[ty + i][tx] = wk[(size_t)(k0 + ty + i) * 1024 + n0 + tx];
  __syncthreads();
#pragma unroll
  for (int i = 0; i < 32; i += 8)
    wt[(size_t)(n0 + ty + i) * 1024 + k0 + tx] = __float2bfloat16(t[tx][ty + i]);
}

// ---------------- bf16 GEMM, C = A[M][K] * B_t[N][K]^T  (m97 structure) ----------------
// 128x128 tile, BK=32, global_load_lds(16B) double-buffered, both-sides XOR swizzle.
// EPI 0: + bias, write bf16 C row-major AND bf16 transposed copy
// EPI 1: * 1/32, masked-fill 1e-9, write fp32
// EPI 2: plain fp32 write
template <int EPI>
__global__ __launch_bounds__(256) void gemm_bt_kernel(
    const bf16* __restrict__ A, int lda, long long A_bs,
    const bf16* __restrict__ B, int ldb, long long B_bs,
    int K,
    void* __restrict__ C, int ldc, long long C_bs,
    const float* __restrict__ bias, bf16* __restrict__ qkv_t,
    const void* __restrict__ mask, const int* __restrict__ flagp, int batch0) {
  __shared__ bf16 sbuf[2][2][128 * 32];  // [dbuf][A|B][128 rows * 32 k]

  const int tid = threadIdx.x;
  const int wave = tid >> 6, lane = tid & 63;
  const int wr = wave >> 1, wc = wave & 1;

  // bijective XCD-aware swizzle of the flattened block id (all grids % 8 == 0)
  const int gx = gridDim.x, gy = gridDim.y;
  const int nwg = gx * gy * gridDim.z;
  int lin = (blockIdx.z * gy + blockIdx.y) * gx + blockIdx.x;
  lin = (lin & 7) * (nwg >> 3) + (lin >> 3);
  const int bx = lin % gx;
  const int by = (lin / gx) % gy;
  const int z = lin / (gx * gy);

  const int m0 = by * 128;
  const int n0 = bx * 128;

  const bf16* Ab = A + (size_t)z * A_bs;
  const bf16* Bb = B + (size_t)z * B_bs;

  int fmode = 0;
  if (EPI == 1) fmode = *flagp;

  // staging geometry: each wave-inst covers 16 rows x 32 k (1 KB), lane L ->
  // row = base + L/4, 16B slot = (L&3) XOR ((row>>1)&3)  [source pre-swizzle]
  const int grow = lane >> 2;
  const int sslot = (lane & 3) ^ ((lane >> 3) & 3);
  const int scol = sslot * 8;

  const size_t a_off0 = (size_t)(m0 + wave * 16 + grow) * lda + scol;
  const size_t a_off1 = a_off0 + (size_t)64 * lda;
  const size_t b_off0 = (size_t)(n0 + wave * 16 + grow) * ldb + scol;
  const size_t b_off1 = b_off0 + (size_t)64 * ldb;
  const int ldsw = wave * 512;  // wave*16 rows * 32 elems

#define STAGE(bufi, kk)                                                          \
  do {                                                                           \
    bf16* sa_ = &sbuf[bufi][0][0];                                               \
    bf16* sb_ = &sbuf[bufi][1][0];                                               \
    __builtin_amdgcn_global_load_lds(GLOBAL_AS(Ab + a_off0 + (kk)),              \
                                     LDS_AS(sa_ + ldsw), 16, 0, 0);              \
    __builtin_amdgcn_global_load_lds(GLOBAL_AS(Ab + a_off1 + (kk)),              \
                                     LDS_AS(sa_ + 2048 + ldsw), 16, 0, 0);       \
    __builtin_amdgcn_global_load_lds(GLOBAL_AS(Bb + b_off0 + (kk)),              \
                                     LDS_AS(sb_ + ldsw), 16, 0, 0);              \
    __builtin_amdgcn_global_load_lds(GLOBAL_AS(Bb + b_off1 + (kk)),              \
                                     LDS_AS(sb_ + 2048 + ldsw), 16, 0, 0);       \
  } while (0)

  f32x4 acc[4][4];
#pragma unroll
  for (int i = 0; i < 4; ++i)
#pragma unroll
    for (int j = 0; j < 4; ++j) acc[i][j] = (f32x4)(0.0f);

  // fragment-read geometry (same XOR on the slot index)
  const int lrow = lane & 15;
  const int slot0 = lane >> 4;  // which 8-elem k-chunk
  const int rsw = (lrow >> 1) & 3;
  const int rdA = (wr * 64 + lrow) * 32 + ((slot0 ^ rsw) * 8);
  const int rdB = (wc * 64 + lrow) * 32 + ((slot0 ^ rsw) * 8);

  STAGE(0, 0);
  const int NT = K >> 5;
  for (int kt = 0; kt < NT; ++kt) {
    __syncthreads();  // drains vmcnt (tile kt staged) + lgkmcnt (kt-1 reads done)
    if (kt + 1 < NT) STAGE((kt + 1) & 1, (size_t)(kt + 1) * 32);
    const bf16* sa = &sbuf[kt & 1][0][0];
    const bf16* sb = &sbuf[kt & 1][1][0];
    short8 af[4], bfr[4];
#pragma unroll
    for (int i = 0; i < 4; ++i) {
      af[i] = *(const short8*)(sa + rdA + i * 512);
      bfr[i] = *(const short8*)(sb + rdB + i * 512);
    }
#pragma unroll
    for (int i = 0; i < 4; ++i)
#pragma unroll
      for (int j = 0; j < 4; ++j)
        acc[i][j] = __builtin_amdgcn_mfma_f32_16x16x32_bf16(af[i], bfr[j], acc[i][j], 0, 0, 0);
  }
#undef STAGE

  // epilogue: C/D layout col = lane&15, row = (lane>>4)*4 + reg  [measured m89]
  const int r0 = (lane >> 4) * 4;
#pragma unroll
  for (int i = 0; i < 4; ++i) {
    const int rowl = m0 + wr * 64 + i * 16 + r0;
#pragma unroll
    for (int j = 0; j < 4; ++j) {
      const int col = n0 + wc * 64 + j * 16 + lrow;
      if (EPI == 0) {
        const float bv = bias[col];
        us4 pack;
#pragma unroll
        for (int r = 0; r < 4; ++r) {
          unsigned short hb = f2bf(acc[i][j][r] + bv);
          ((unsigned short*)C)[(size_t)(rowl + r) * ldc + col] = hb;
          pack[r] = hb;
        }
        const int bb = rowl >> 11, s = rowl & 2047;
        *(us4*)((unsigned short*)qkv_t + (size_t)bb * (1024ll * 2048) +
                (size_t)col * 2048 + s) = pack;
      } else if (EPI == 1) {
#pragma unroll
        for (int r = 0; r < 4; ++r) {
          const int row = rowl + r;
          float v = acc[i][j][r] * 0.03125f;
          const size_t midx = (size_t)(batch0 + z) * (2048ull * 2048) +
                              (size_t)row * 2048 + (size_t)col;
          int mv;
          if (fmode == 0) mv = ((const int*)mask)[midx];
          else if (fmode == 1) mv = (int)((const unsigned char*)mask)[midx];
          else mv = (((const float*)mask)[midx] != 0.0f);
          if (mv) v = 1e-9f;
          ((float*)C + (size_t)z * C_bs)[(size_t)row * ldc + col] = v;
        }
      } else {
#pragma unroll
        for (int r = 0; r < 4; ++r)
          ((float*)C + (size_t)z * C_bs)[(size_t)(rowl + r) * ldc + col] = acc[i][j][r];
      }
    }
  }
}

// ---------------- in-place row softmax: fp32 scores -> bf16 weights ----------------
__global__ __launch_bounds__(256) void softmax_kernel(float* __restrict__ scores) {
  const int row = blockIdx.x;
  float* base = scores + (size_t)row * 2048;
  const int tid = threadIdx.x;
  const int wave = tid >> 6, lane = tid & 63;
  f32x4 v0 = *(const f32x4*)(base + tid * 4);
  f32x4 v1 = *(const f32x4*)(base + 1024 + tid * 4);
  float m = v0[0];
#pragma unroll
  for (int r = 1; r < 4; ++r) m = fmaxf(m, v0[r]);
#pragma unroll
  for (int r = 0; r < 4; ++r) m = fmaxf(m, v1[r]);
#pragma unroll
  for (int o = 32; o >= 1; o >>= 1) m = fmaxf(m, __shfl_xor(m, o));
  __shared__ float red[8];
  if (lane == 0) red[wave] = m;
  __syncthreads();
  m = fmaxf(fmaxf(red[0], red[1]), fmaxf(red[2], red[3]));
  float sum = 0.f;
  float e0[4], e1[4];
#pragma unroll
  for (int r = 0; r < 4; ++r) { e0[r] = expf(v0[r] - m); sum += e0[r]; }
#pragma unroll
  for (int r = 0; r < 4; ++r) { e1[r] = expf(v1[r] - m); sum += e1[r]; }
#pragma unroll
  for (int o = 32; o >= 1; o >>= 1) sum += __shfl_xor(sum, o);
  if (lane == 0) red[4 + wave] = sum;
  __syncthreads();
  const float inv = 1.0f / (red[4] + red[5] + red[6] + red[7]);
  unsigned short* ob = (unsigned short*)base;
  us4 p0, p1;
#pragma unroll
  for (int r = 0; r < 4; ++r) { p0[r] = f2bf(e0[r] * inv); p1[r] = f2bf(e1[r] * inv); }
  *(us4*)(ob + tid * 4) = p0;
  *(us4*)(ob + 1024 + tid * 4) = p1;
}

// ---------------- launcher ----------------
extern "C" void kernel_launch(void* const* d_in, const int* in_sizes, int n_in,
                              void* d_out, int out_size, void* d_ws, size_t ws_size,
                              hipStream_t stream) {
  const float* tensor = (const float*)d_in[0];
  const void* mask = d_in[1];
  const float* lnw = (const float*)d_in[2];
  const float* lnb = (const float*)d_in[3];
  const float* wk = (const float*)d_in[4];
  const float* bk = (const float*)d_in[5];
  float* out = (float*)d_out;

  // ws layout (bytes):
  //   0     : Wk_t bf16 [1024][1024]                  (2 MB)
  //   2 MB  : qkv_n bf16 [8192][1024]                 (16 MB)
  //   18 MB : qkv_t bf16 [4][1024][2048]              (16 MB)
  //   34 MB : x bf16 (dead after gemm0) / scores fp32 (32 MB)
  //   66 MB : mask-dtype flag                          (4 B)
  char* ws = (char*)d_ws;
  bf16* wkt = (bf16*)(ws);
  bf16* qkvn = (bf16*)(ws + (2ll << 20));
  bf16* qkvt = (bf16*)(ws + (18ll << 20));
  bf16* xbf = (bf16*)(ws + (34ll << 20));
  float* scores = (float*)(ws + (34ll << 20));
  int* flag = (int*)(ws + (66ll << 20));

  detect_mask_kernel<<<1, 256, 0, stream>>>((const unsigned int*)mask, flag);
  pe_ln_kernel<<<8192, 256, 0, stream>>>(tensor, lnw, lnb, xbf);
  wk_to_bf16t_kernel<<<dim3(32, 32), 256, 0, stream>>>(wk, wkt);

  // qkv = x @ Wk + bk   (M=8192, N=1024, K=1024); dual-write row-major + transposed
  gemm_bt_kernel<0><<<dim3(8, 64, 1), 256, 0, stream>>>(
      xbf, 1024, 0, wkt, 1024, 0, 1024,
      (void*)qkvn, 1024, 0, bk, qkvt, nullptr, nullptr, 0);

  for (int c = 0; c < 2; ++c) {
    // scores = qkv @ qkv^T / 32, mask-fill 1e-9  (per batch: M=N=2048, K=1024)
    gemm_bt_kernel<1><<<dim3(16, 16, 2), 256, 0, stream>>>(
        qkvn + (size_t)c * 2 * 2048 * 1024, 1024, 2048ll * 1024,
        qkvn + (size_t)c * 2 * 2048 * 1024, 1024, 2048ll * 1024, 1024,
        (void*)scores, 2048, 2048ll * 2048, nullptr, nullptr, mask, flag, c * 2);
    // softmax rows, in-place fp32 -> bf16 (row stride stays 4096 bf16 elements)
    softmax_kernel<<<4096, 256, 0, stream>>>(scores);
    // out = weights @ qkv  (per batch: M=2048, N=1024, K=2048)
    gemm_bt_kernel<2><<<dim3(8, 16, 2), 256, 0, stream>>>(
        (const bf16*)scores, 4096, 2048ll * 4096,
        qkvt + (size_t)c * 2 * 1024 * 2048, 2048, 1024ll * 2048, 2048,
        (void*)(out + (size_t)c * 2 * 2048 * 1024), 1024, 2048ll * 1024,
        nullptr, nullptr, nullptr, nullptr, 0);
  }
}

// Round 3
// 193.312 us; speedup vs baseline: 1.2241x; 1.1150x over previous
//
#include <hip/hip_runtime.h>
#include <hip/hip_bf16.h>

#define S_LEN 2048
#define D_DIM 1024

typedef float f32x4 __attribute__((ext_vector_type(4)));
typedef short short8 __attribute__((ext_vector_type(8)));
typedef unsigned short us4 __attribute__((ext_vector_type(4)));

using bf16 = __hip_bfloat16;

#define GLOBAL_AS(p) ((const __attribute__((address_space(1))) void*)(p))
#define LDS_AS(p) ((__attribute__((address_space(3))) void*)(p))

static __device__ __forceinline__ unsigned short f2bf(float f) {
  bf16 h = __float2bfloat16(f);
  return *reinterpret_cast<unsigned short*>(&h);
}
static __device__ __forceinline__ float bf2f(unsigned short u) {
  unsigned int w = ((unsigned int)u) << 16;
  return __builtin_bit_cast(float, w);
}

// ---------------- mask dtype probe: 0=int32, 1=uint8, 2=float32 ----------------
__global__ void detect_mask_kernel(const unsigned int* __restrict__ m, int* __restrict__ flag) {
  __shared__ int sh;
  if (threadIdx.x == 0) sh = 0;
  __syncthreads();
  int f = 0;
  for (int i = threadIdx.x; i < 4096; i += 256) {
    unsigned int w = m[i];
    if (w == 0x3f800000u) f |= 2;
    if (w & 0xFFFFFF00u) f |= 1;
  }
  if (f) atomicOr(&sh, f);
  __syncthreads();
  if (threadIdx.x == 0) *flag = (sh & 2) ? 2 : ((sh & 1) ? 1 : 0);
}

// ---------------- fused positional-encoding + LayerNorm -> bf16 ----------------
__global__ __launch_bounds__(256) void pe_ln_kernel(
    const float* __restrict__ x, const float* __restrict__ lnw,
    const float* __restrict__ lnb, bf16* __restrict__ out) {
  const int row = blockIdx.x;
  const int s = row & (S_LEN - 1);
  const int tid = threadIdx.x;
  const float pos = (float)s;
  const float* base = x + (size_t)row * D_DIM;

  f32x4 v = *(const f32x4*)(base + tid * 4);
  float h[4];
#pragma unroll
  for (int r = 0; r < 4; ++r) {
    int d = tid * 4 + r;
    float dv = (float)d * (2.0f / 1024.0f);
    float freq = exp2f(dv * -13.287712379549449f);
    float pe = pos * freq;
    float pv = (d & 1) ? cosf(pe) : sinf(pe);
    h[r] = pv + v[r];
  }
  float ss = h[0] + h[1] + h[2] + h[3];
#pragma unroll
  for (int o = 32; o >= 1; o >>= 1) ss += __shfl_xor(ss, o);
  __shared__ float red[8];
  const int wave = tid >> 6, lane = tid & 63;
  if (lane == 0) red[wave] = ss;
  __syncthreads();
  const float mu = (red[0] + red[1] + red[2] + red[3]) * (1.0f / 1024.0f);
  float sq = 0.f;
#pragma unroll
  for (int r = 0; r < 4; ++r) { float d0 = h[r] - mu; sq += d0 * d0; }
#pragma unroll
  for (int o = 32; o >= 1; o >>= 1) sq += __shfl_xor(sq, o);
  if (lane == 0) red[4 + wave] = sq;
  __syncthreads();
  const float var = (red[4] + red[5] + red[6] + red[7]) * (1.0f / 1024.0f);
  const float inv = rsqrtf(var + 1e-5f);
  f32x4 wv = *(const f32x4*)(lnw + tid * 4);
  f32x4 bv = *(const f32x4*)(lnb + tid * 4);
  us4 o4;
#pragma unroll
  for (int r = 0; r < 4; ++r) o4[r] = f2bf((h[r] - mu) * inv * wv[r] + bv[r]);
  *(us4*)((unsigned short*)out + (size_t)row * D_DIM + tid * 4) = o4;
}

// ---------------- Wk fp32 [K][N] -> bf16 transposed [N][K] ----------------
__global__ __launch_bounds__(256) void wk_to_bf16t_kernel(const float* __restrict__ wk,
                                                          bf16* __restrict__ wt) {
  __shared__ float t[32][33];
  const int n0 = blockIdx.x * 32, k0 = blockIdx.y * 32;
  const int tx = threadIdx.x & 31, ty = threadIdx.x >> 5;
#pragma unroll
  for (int i = 0; i < 32; i += 8)
    t[ty + i][tx] = wk[(size_t)(k0 + ty + i) * 1024 + n0 + tx];
  __syncthreads();
#pragma unroll
  for (int i = 0; i < 32; i += 8)
    wt[(size_t)(n0 + ty + i) * 1024 + k0 + tx] = __float2bfloat16(t[tx][ty + i]);
}

// ---------------- bf16 GEMM, C = A[M][K] * B_t[N][K]^T ----------------
// 128x128 tile, BK=32, global_load_lds(16B), counted-vmcnt 2-deep pipeline (T4),
// both-sides XOR swizzle on LDS 16B slots.
// EPI 0: + bias, write bf16 C row-major AND bf16 transposed copy
// EPI 1: * 1/32, masked-fill 1e-9, write bf16
// EPI 2: plain fp32 write
template <int EPI>
__global__ __launch_bounds__(256) void gemm_bt_kernel(
    const bf16* __restrict__ A, int lda, long long A_bs,
    const bf16* __restrict__ B, int ldb, long long B_bs,
    int K,
    void* __restrict__ C, int ldc, long long C_bs,
    const float* __restrict__ bias, bf16* __restrict__ qkv_t,
    const void* __restrict__ mask, const int* __restrict__ flagp, int batch0) {
  __shared__ bf16 sbuf[2][2][128 * 32];  // [dbuf][A|B][128 rows * 32 k] = 32 KB

  const int tid = threadIdx.x;
  const int wave = tid >> 6, lane = tid & 63;
  const int wr = wave >> 1, wc = wave & 1;

  // bijective XCD-aware swizzle of the flattened block id (all grids % 8 == 0)
  const int gx = gridDim.x, gy = gridDim.y;
  const int nwg = gx * gy * gridDim.z;
  int lin = (blockIdx.z * gy + blockIdx.y) * gx + blockIdx.x;
  lin = (lin & 7) * (nwg >> 3) + (lin >> 3);
  const int bx = lin % gx;
  const int by = (lin / gx) % gy;
  const int z = lin / (gx * gy);

  const int m0 = by * 128;
  const int n0 = bx * 128;

  const bf16* Ab = A + (size_t)z * A_bs;
  const bf16* Bb = B + (size_t)z * B_bs;

  int fmode = 0;
  if (EPI == 1) fmode = *flagp;

  // staging: wave covers 16 rows x 32 k (1 KB) per inst; lane L -> row base+L/4,
  // 16B slot = (L&3) XOR ((row>>1)&3)   [source pre-swizzle, LDS dest linear]
  const int grow = lane >> 2;
  const int scol = ((lane & 3) ^ ((lane >> 3) & 3)) * 8;

  const size_t a_off0 = (size_t)(m0 + wave * 16 + grow) * lda + scol;
  const size_t a_off1 = a_off0 + (size_t)64 * lda;
  const size_t b_off0 = (size_t)(n0 + wave * 16 + grow) * ldb + scol;
  const size_t b_off1 = b_off0 + (size_t)64 * ldb;
  const int ldsw = wave * 512;

#define STAGE(bufi, kk)                                                          \
  do {                                                                           \
    bf16* sa_ = &sbuf[bufi][0][0];                                               \
    bf16* sb_ = &sbuf[bufi][1][0];                                               \
    __builtin_amdgcn_global_load_lds(GLOBAL_AS(Ab + a_off0 + (kk)),              \
                                     LDS_AS(sa_ + ldsw), 16, 0, 0);              \
    __builtin_amdgcn_global_load_lds(GLOBAL_AS(Ab + a_off1 + (kk)),              \
                                     LDS_AS(sa_ + 2048 + ldsw), 16, 0, 0);       \
    __builtin_amdgcn_global_load_lds(GLOBAL_AS(Bb + b_off0 + (kk)),              \
                                     LDS_AS(sb_ + ldsw), 16, 0, 0);              \
    __builtin_amdgcn_global_load_lds(GLOBAL_AS(Bb + b_off1 + (kk)),              \
                                     LDS_AS(sb_ + 2048 + ldsw), 16, 0, 0);       \
  } while (0)

  f32x4 acc[4][4];
#pragma unroll
  for (int i = 0; i < 4; ++i)
#pragma unroll
    for (int j = 0; j < 4; ++j) acc[i][j] = (f32x4)(0.0f);

  // fragment-read geometry (same XOR on the 16B slot index)
  const int lrow = lane & 15;
  const int slot0 = lane >> 4;
  const int rsw = (lrow >> 1) & 3;
  const int rdA = (wr * 64 + lrow) * 32 + ((slot0 ^ rsw) * 8);
  const int rdB = (wc * 64 + lrow) * 32 + ((slot0 ^ rsw) * 8);

  const int NT = K >> 5;
  STAGE(0, 0);
  STAGE(1, 32);
  for (int kt = 0; kt < NT; ++kt) {
    // tile kt's 4 loads complete; tile kt+1's 4 stay in flight (never drain to 0)
    if (kt < NT - 1) asm volatile("s_waitcnt vmcnt(4)" ::: "memory");
    else             asm volatile("s_waitcnt vmcnt(0)" ::: "memory");
    __builtin_amdgcn_s_barrier();
    const bf16* sa = &sbuf[kt & 1][0][0];
    const bf16* sb = &sbuf[kt & 1][1][0];
    short8 af[4], bfr[4];
#pragma unroll
    for (int i = 0; i < 4; ++i) {
      af[i] = *(const short8*)(sa + rdA + i * 512);
      bfr[i] = *(const short8*)(sb + rdB + i * 512);
    }
#pragma unroll
    for (int i = 0; i < 4; ++i)
#pragma unroll
      for (int j = 0; j < 4; ++j)
        acc[i][j] = __builtin_amdgcn_mfma_f32_16x16x32_bf16(af[i], bfr[j], acc[i][j], 0, 0, 0);
    if (kt + 2 < NT) {
      __builtin_amdgcn_s_barrier();  // all waves' reads of buf[kt&1] are done (lgkmcnt
                                     // forced before their MFMAs) -> safe to overwrite
      STAGE(kt & 1, (size_t)(kt + 2) * 32);
    }
  }
#undef STAGE

  // epilogue: C/D layout col = lane&15, row = (lane>>4)*4 + reg  [measured m89]
  const int r0 = (lane >> 4) * 4;
#pragma unroll
  for (int i = 0; i < 4; ++i) {
    const int rowl = m0 + wr * 64 + i * 16 + r0;
#pragma unroll
    for (int j = 0; j < 4; ++j) {
      const int col = n0 + wc * 64 + j * 16 + lrow;
      if (EPI == 0) {
        const float bv = bias[col];
        us4 pack;
#pragma unroll
        for (int r = 0; r < 4; ++r) {
          unsigned short hb = f2bf(acc[i][j][r] + bv);
          ((unsigned short*)C)[(size_t)(rowl + r) * ldc + col] = hb;
          pack[r] = hb;
        }
        const int bb = rowl >> 11, s = rowl & 2047;
        *(us4*)((unsigned short*)qkv_t + (size_t)bb * (1024ll * 2048) +
                (size_t)col * 2048 + s) = pack;
      } else if (EPI == 1) {
#pragma unroll
        for (int r = 0; r < 4; ++r) {
          const int row = rowl + r;
          float v = acc[i][j][r] * 0.03125f;
          const size_t midx = (size_t)(batch0 + z) * (2048ull * 2048) +
                              (size_t)row * 2048 + (size_t)col;
          int mv;
          if (fmode == 0) mv = ((const int*)mask)[midx];
          else if (fmode == 1) mv = (int)((const unsigned char*)mask)[midx];
          else mv = (((const float*)mask)[midx] != 0.0f);
          if (mv) v = 1e-9f;
          ((unsigned short*)C + (size_t)z * C_bs)[(size_t)row * ldc + col] = f2bf(v);
        }
      } else {
#pragma unroll
        for (int r = 0; r < 4; ++r)
          ((float*)C + (size_t)z * C_bs)[(size_t)(rowl + r) * ldc + col] = acc[i][j][r];
      }
    }
  }
}

// ---------------- in-place row softmax on bf16 scores ----------------
__global__ __launch_bounds__(256) void softmax_kernel(unsigned short* __restrict__ scores) {
  const int row = blockIdx.x;  // 8192 rows
  unsigned short* base = scores + (size_t)row * 2048;
  const int tid = threadIdx.x;
  const int wave = tid >> 6, lane = tid & 63;
  short8 v = *(const short8*)(base + tid * 8);
  float x[8];
#pragma unroll
  for (int r = 0; r < 8; ++r) x[r] = bf2f((unsigned short)v[r]);
  float m = x[0];
#pragma unroll
  for (int r = 1; r < 8; ++r) m = fmaxf(m, x[r]);
#pragma unroll
  for (int o = 32; o >= 1; o >>= 1) m = fmaxf(m, __shfl_xor(m, o));
  __shared__ float red[8];
  if (lane == 0) red[wave] = m;
  __syncthreads();
  m = fmaxf(fmaxf(red[0], red[1]), fmaxf(red[2], red[3]));
  float e[8], sum = 0.f;
#pragma unroll
  for (int r = 0; r < 8; ++r) { e[r] = expf(x[r] - m); sum += e[r]; }
#pragma unroll
  for (int o = 32; o >= 1; o >>= 1) sum += __shfl_xor(sum, o);
  if (lane == 0) red[4 + wave] = sum;
  __syncthreads();
  const float inv = 1.0f / (red[4] + red[5] + red[6] + red[7]);
  short8 o8;
#pragma unroll
  for (int r = 0; r < 8; ++r) o8[r] = (short)f2bf(e[r] * inv);
  *(short8*)(base + tid * 8) = o8;
}

// ---------------- launcher ----------------
extern "C" void kernel_launch(void* const* d_in, const int* in_sizes, int n_in,
                              void* d_out, int out_size, void* d_ws, size_t ws_size,
                              hipStream_t stream) {
  const float* tensor = (const float*)d_in[0];
  const void* mask = d_in[1];
  const float* lnw = (const float*)d_in[2];
  const float* lnb = (const float*)d_in[3];
  const float* wk = (const float*)d_in[4];
  const float* bk = (const float*)d_in[5];
  float* out = (float*)d_out;

  // ws layout (bytes):
  //   0     : Wk_t bf16 [1024][1024]                    (2 MB)
  //   2 MB  : qkv_n bf16 [8192][1024]                   (16 MB)
  //   18 MB : qkv_t bf16 [4][1024][2048]                (16 MB)
  //   34 MB : x bf16 (dead after gemm0) / scores bf16 [4][2048][2048] (32 MB)
  //   66 MB : mask-dtype flag                            (4 B)
  char* ws = (char*)d_ws;
  bf16* wkt = (bf16*)(ws);
  bf16* qkvn = (bf16*)(ws + (2ll << 20));
  bf16* qkvt = (bf16*)(ws + (18ll << 20));
  bf16* xbf = (bf16*)(ws + (34ll << 20));
  unsigned short* scores = (unsigned short*)(ws + (34ll << 20));
  int* flag = (int*)(ws + (66ll << 20));

  detect_mask_kernel<<<1, 256, 0, stream>>>((const unsigned int*)mask, flag);
  pe_ln_kernel<<<8192, 256, 0, stream>>>(tensor, lnw, lnb, xbf);
  wk_to_bf16t_kernel<<<dim3(32, 32), 256, 0, stream>>>(wk, wkt);

  // qkv = x @ Wk + bk   (M=8192, N=1024, K=1024); dual-write row-major + transposed
  gemm_bt_kernel<0><<<dim3(8, 64, 1), 256, 0, stream>>>(
      xbf, 1024, 0, wkt, 1024, 0, 1024,
      (void*)qkvn, 1024, 0, bk, qkvt, nullptr, nullptr, 0);

  // scores = qkv @ qkv^T / 32, mask-fill 1e-9, bf16  (all 4 batches: M=N=2048, K=1024)
  gemm_bt_kernel<1><<<dim3(16, 16, 4), 256, 0, stream>>>(
      qkvn, 1024, 2048ll * 1024,
      qkvn, 1024, 2048ll * 1024, 1024,
      (void*)scores, 2048, 2048ll * 2048, nullptr, nullptr, mask, flag, 0);

  // softmax rows, in-place bf16 -> bf16 (4*2048 rows)
  softmax_kernel<<<8192, 256, 0, stream>>>(scores);

  // out = weights @ qkv  (all 4 batches: M=2048, N=1024, K=2048)
  gemm_bt_kernel<2><<<dim3(8, 16, 4), 256, 0, stream>>>(
      (const bf16*)scores, 2048, 2048ll * 2048,
      qkvt, 2048, 1024ll * 2048, 2048,
      (void*)out, 1024, 2048ll * 1024,
      nullptr, nullptr, nullptr, nullptr, 0);
}

// Round 4
// 166.970 us; speedup vs baseline: 1.4172x; 1.1578x over previous
//
#include <hip/hip_runtime.h>
#include <hip/hip_bf16.h>

#define S_LEN 2048
#define D_DIM 1024

typedef float f32x4 __attribute__((ext_vector_type(4)));
typedef short short8 __attribute__((ext_vector_type(8)));
typedef unsigned short us4 __attribute__((ext_vector_type(4)));
typedef unsigned int u32x4 __attribute__((ext_vector_type(4)));
typedef unsigned short us4v __attribute__((ext_vector_type(4)));

using bf16 = __hip_bfloat16;

#define GLOBAL_AS(p) ((const __attribute__((address_space(1))) void*)(p))
#define LDS_AS(p) ((__attribute__((address_space(3))) void*)(p))

static __device__ __forceinline__ unsigned short f2bf(float f) {
  bf16 h = __float2bfloat16(f);
  return *reinterpret_cast<unsigned short*>(&h);
}
static __device__ __forceinline__ float bf2f(unsigned short u) {
  unsigned int w = ((unsigned int)u) << 16;
  return __builtin_bit_cast(float, w);
}

// ---------------- mask dtype probe: 0=int32, 1=uint8, 2=float32 ----------------
__global__ void detect_mask_kernel(const unsigned int* __restrict__ m, int* __restrict__ flag) {
  __shared__ int sh;
  if (threadIdx.x == 0) sh = 0;
  __syncthreads();
  int f = 0;
  for (int i = threadIdx.x; i < 4096; i += 256) {
    unsigned int w = m[i];
    if (w == 0x3f800000u) f |= 2;
    if (w & 0xFFFFFF00u) f |= 1;
  }
  if (f) atomicOr(&sh, f);
  __syncthreads();
  if (threadIdx.x == 0) *flag = (sh & 2) ? 2 : ((sh & 1) ? 1 : 0);
}

// ---------------- fused positional-encoding + LayerNorm -> bf16 ----------------
__global__ __launch_bounds__(256) void pe_ln_kernel(
    const float* __restrict__ x, const float* __restrict__ lnw,
    const float* __restrict__ lnb, bf16* __restrict__ out) {
  const int row = blockIdx.x;
  const int s = row & (S_LEN - 1);
  const int tid = threadIdx.x;
  const float pos = (float)s;
  const float* base = x + (size_t)row * D_DIM;

  f32x4 v = *(const f32x4*)(base + tid * 4);
  float h[4];
#pragma unroll
  for (int r = 0; r < 4; ++r) {
    int d = tid * 4 + r;
    float dv = (float)d * (2.0f / 1024.0f);
    float freq = exp2f(dv * -13.287712379549449f);
    float pe = pos * freq;
    float pv = (d & 1) ? cosf(pe) : sinf(pe);
    h[r] = pv + v[r];
  }
  float ss = h[0] + h[1] + h[2] + h[3];
#pragma unroll
  for (int o = 32; o >= 1; o >>= 1) ss += __shfl_xor(ss, o);
  __shared__ float red[8];
  const int wave = tid >> 6, lane = tid & 63;
  if (lane == 0) red[wave] = ss;
  __syncthreads();
  const float mu = (red[0] + red[1] + red[2] + red[3]) * (1.0f / 1024.0f);
  float sq = 0.f;
#pragma unroll
  for (int r = 0; r < 4; ++r) { float d0 = h[r] - mu; sq += d0 * d0; }
#pragma unroll
  for (int o = 32; o >= 1; o >>= 1) sq += __shfl_xor(sq, o);
  if (lane == 0) red[4 + wave] = sq;
  __syncthreads();
  const float var = (red[4] + red[5] + red[6] + red[7]) * (1.0f / 1024.0f);
  const float inv = rsqrtf(var + 1e-5f);
  f32x4 wv = *(const f32x4*)(lnw + tid * 4);
  f32x4 bv = *(const f32x4*)(lnb + tid * 4);
  us4 o4;
#pragma unroll
  for (int r = 0; r < 4; ++r) o4[r] = f2bf((h[r] - mu) * inv * wv[r] + bv[r]);
  *(us4*)((unsigned short*)out + (size_t)row * D_DIM + tid * 4) = o4;
}

// ---------------- Wk fp32 [K][N] -> bf16 transposed [N][K] ----------------
__global__ __launch_bounds__(256) void wk_to_bf16t_kernel(const float* __restrict__ wk,
                                                          bf16* __restrict__ wt) {
  __shared__ float t[32][33];
  const int n0 = blockIdx.x * 32, k0 = blockIdx.y * 32;
  const int tx = threadIdx.x & 31, ty = threadIdx.x >> 5;
#pragma unroll
  for (int i = 0; i < 32; i += 8)
    t[ty + i][tx] = wk[(size_t)(k0 + ty + i) * 1024 + n0 + tx];
  __syncthreads();
#pragma unroll
  for (int i = 0; i < 32; i += 8)
    wt[(size_t)(n0 + ty + i) * 1024 + k0 + tx] = __float2bfloat16(t[tx][ty + i]);
}

// ---------------- bf16 GEMM, C = A[M][K] * B_t[N][K]^T ----------------
// 128x128 tile, BK=32, global_load_lds(16B), counted-vmcnt 2-deep pipeline (T4),
// both-sides XOR swizzle on LDS 16B slots.
// EPI 0: + bias, write bf16 C row-major AND bf16 transposed copy
// EPI 1: * 1/32, write bf16 (mask applied later in softmax)
// EPI 2: plain fp32 write
template <int EPI>
__global__ __launch_bounds__(256) void gemm_bt_kernel(
    const bf16* __restrict__ A, int lda, long long A_bs,
    const bf16* __restrict__ B, int ldb, long long B_bs,
    int K,
    void* __restrict__ C, int ldc, long long C_bs,
    const float* __restrict__ bias, bf16* __restrict__ qkv_t) {
  __shared__ bf16 sbuf[2][2][128 * 32];  // [dbuf][A|B][128 rows * 32 k] = 32 KB

  const int tid = threadIdx.x;
  const int wave = tid >> 6, lane = tid & 63;
  const int wr = wave >> 1, wc = wave & 1;

  // bijective XCD-aware swizzle of the flattened block id (all grids % 8 == 0)
  const int gx = gridDim.x, gy = gridDim.y;
  const int nwg = gx * gy * gridDim.z;
  int lin = (blockIdx.z * gy + blockIdx.y) * gx + blockIdx.x;
  lin = (lin & 7) * (nwg >> 3) + (lin >> 3);
  const int bx = lin % gx;
  const int by = (lin / gx) % gy;
  const int z = lin / (gx * gy);

  const int m0 = by * 128;
  const int n0 = bx * 128;

  const bf16* Ab = A + (size_t)z * A_bs;
  const bf16* Bb = B + (size_t)z * B_bs;

  // staging: wave covers 16 rows x 32 k (1 KB) per inst; lane L -> row base+L/4,
  // 16B slot = (L&3) XOR ((row>>1)&3)   [source pre-swizzle, LDS dest linear]
  const int grow = lane >> 2;
  const int scol = ((lane & 3) ^ ((lane >> 3) & 3)) * 8;

  const size_t a_off0 = (size_t)(m0 + wave * 16 + grow) * lda + scol;
  const size_t a_off1 = a_off0 + (size_t)64 * lda;
  const size_t b_off0 = (size_t)(n0 + wave * 16 + grow) * ldb + scol;
  const size_t b_off1 = b_off0 + (size_t)64 * ldb;
  const int ldsw = wave * 512;

#define STAGE(bufi, kk)                                                          \
  do {                                                                           \
    bf16* sa_ = &sbuf[bufi][0][0];                                               \
    bf16* sb_ = &sbuf[bufi][1][0];                                               \
    __builtin_amdgcn_global_load_lds(GLOBAL_AS(Ab + a_off0 + (kk)),              \
                                     LDS_AS(sa_ + ldsw), 16, 0, 0);              \
    __builtin_amdgcn_global_load_lds(GLOBAL_AS(Ab + a_off1 + (kk)),              \
                                     LDS_AS(sa_ + 2048 + ldsw), 16, 0, 0);       \
    __builtin_amdgcn_global_load_lds(GLOBAL_AS(Bb + b_off0 + (kk)),              \
                                     LDS_AS(sb_ + ldsw), 16, 0, 0);              \
    __builtin_amdgcn_global_load_lds(GLOBAL_AS(Bb + b_off1 + (kk)),              \
                                     LDS_AS(sb_ + 2048 + ldsw), 16, 0, 0);       \
  } while (0)

  f32x4 acc[4][4];
#pragma unroll
  for (int i = 0; i < 4; ++i)
#pragma unroll
    for (int j = 0; j < 4; ++j) acc[i][j] = (f32x4)(0.0f);

  // fragment-read geometry (same XOR on the 16B slot index)
  const int lrow = lane & 15;
  const int slot0 = lane >> 4;
  const int rsw = (lrow >> 1) & 3;
  const int rdA = (wr * 64 + lrow) * 32 + ((slot0 ^ rsw) * 8);
  const int rdB = (wc * 64 + lrow) * 32 + ((slot0 ^ rsw) * 8);

  const int NT = K >> 5;
  STAGE(0, 0);
  STAGE(1, 32);
  for (int kt = 0; kt < NT; ++kt) {
    // tile kt's 4 loads complete; tile kt+1's 4 stay in flight (never drain to 0)
    if (kt < NT - 1) asm volatile("s_waitcnt vmcnt(4)" ::: "memory");
    else             asm volatile("s_waitcnt vmcnt(0)" ::: "memory");
    __builtin_amdgcn_s_barrier();
    const bf16* sa = &sbuf[kt & 1][0][0];
    const bf16* sb = &sbuf[kt & 1][1][0];
    short8 af[4], bfr[4];
#pragma unroll
    for (int i = 0; i < 4; ++i) {
      af[i] = *(const short8*)(sa + rdA + i * 512);
      bfr[i] = *(const short8*)(sb + rdB + i * 512);
    }
#pragma unroll
    for (int i = 0; i < 4; ++i)
#pragma unroll
      for (int j = 0; j < 4; ++j)
        acc[i][j] = __builtin_amdgcn_mfma_f32_16x16x32_bf16(af[i], bfr[j], acc[i][j], 0, 0, 0);
    if (kt + 2 < NT) {
      __builtin_amdgcn_s_barrier();  // all waves' reads of buf[kt&1] done -> overwrite ok
      STAGE(kt & 1, (size_t)(kt + 2) * 32);
    }
  }
#undef STAGE

  // epilogue: C/D layout col = lane&15, row = (lane>>4)*4 + reg  [measured m89]
  const int r0 = (lane >> 4) * 4;
#pragma unroll
  for (int i = 0; i < 4; ++i) {
    const int rowl = m0 + wr * 64 + i * 16 + r0;
#pragma unroll
    for (int j = 0; j < 4; ++j) {
      const int col = n0 + wc * 64 + j * 16 + lrow;
      if (EPI == 0) {
        const float bv = bias[col];
        us4 pack;
#pragma unroll
        for (int r = 0; r < 4; ++r) {
          unsigned short hb = f2bf(acc[i][j][r] + bv);
          ((unsigned short*)C)[(size_t)(rowl + r) * ldc + col] = hb;
          pack[r] = hb;
        }
        const int bb = rowl >> 11, s = rowl & 2047;
        *(us4*)((unsigned short*)qkv_t + (size_t)bb * (1024ll * 2048) +
                (size_t)col * 2048 + s) = pack;
      } else if (EPI == 1) {
#pragma unroll
        for (int r = 0; r < 4; ++r)
          ((unsigned short*)C + (size_t)z * C_bs)[(size_t)(rowl + r) * ldc + col] =
              f2bf(acc[i][j][r] * 0.03125f);
      } else {
#pragma unroll
        for (int r = 0; r < 4; ++r)
          ((float*)C + (size_t)z * C_bs)[(size_t)(rowl + r) * ldc + col] = acc[i][j][r];
      }
    }
  }
}

// ---------------- fused mask + in-place row softmax on bf16 scores ----------------
// masked_fill(scores, mask, 1e-9) then softmax — mask read here at streaming BW.
__global__ __launch_bounds__(256) void softmax_kernel(
    unsigned short* __restrict__ scores, const void* __restrict__ mask,
    const int* __restrict__ flagp) {
  const int row = blockIdx.x;  // 8192 rows = b*2048 + q; mask flat idx row*2048 + s
  const int fmode = *flagp;
  unsigned short* base = scores + (size_t)row * 2048;
  const int tid = threadIdx.x;
  const int wave = tid >> 6, lane = tid & 63;

  short8 v = *(const short8*)(base + tid * 8);
  float x[8];
#pragma unroll
  for (int r = 0; r < 8; ++r) x[r] = bf2f((unsigned short)v[r]);

  const size_t mofs = (size_t)row * 2048 + tid * 8;
  if (fmode == 0) {
    const unsigned int* mp = (const unsigned int*)mask + mofs;
    u32x4 m0 = *(const u32x4*)mp;
    u32x4 m1 = *(const u32x4*)(mp + 4);
#pragma unroll
    for (int r = 0; r < 4; ++r) { if (m0[r]) x[r] = 1e-9f; }
#pragma unroll
    for (int r = 0; r < 4; ++r) { if (m1[r]) x[4 + r] = 1e-9f; }
  } else if (fmode == 1) {
    const unsigned char* mp = (const unsigned char*)mask + mofs;
    us4v mb = *(const us4v*)mp;  // 8 bytes
#pragma unroll
    for (int r = 0; r < 4; ++r) {
      if (mb[r] & 0x00FF) x[2 * r] = 1e-9f;
      if (mb[r] & 0xFF00) x[2 * r + 1] = 1e-9f;
    }
  } else {
    const float* mp = (const float*)mask + mofs;
    f32x4 m0 = *(const f32x4*)mp;
    f32x4 m1 = *(const f32x4*)(mp + 4);
#pragma unroll
    for (int r = 0; r < 4; ++r) { if (m0[r] != 0.0f) x[r] = 1e-9f; }
#pragma unroll
    for (int r = 0; r < 4; ++r) { if (m1[r] != 0.0f) x[4 + r] = 1e-9f; }
  }

  float m = x[0];
#pragma unroll
  for (int r = 1; r < 8; ++r) m = fmaxf(m, x[r]);
#pragma unroll
  for (int o = 32; o >= 1; o >>= 1) m = fmaxf(m, __shfl_xor(m, o));
  __shared__ float red[8];
  if (lane == 0) red[wave] = m;
  __syncthreads();
  m = fmaxf(fmaxf(red[0], red[1]), fmaxf(red[2], red[3]));
  float e[8], sum = 0.f;
#pragma unroll
  for (int r = 0; r < 8; ++r) { e[r] = expf(x[r] - m); sum += e[r]; }
#pragma unroll
  for (int o = 32; o >= 1; o >>= 1) sum += __shfl_xor(sum, o);
  if (lane == 0) red[4 + wave] = sum;
  __syncthreads();
  const float inv = 1.0f / (red[4] + red[5] + red[6] + red[7]);
  short8 o8;
#pragma unroll
  for (int r = 0; r < 8; ++r) o8[r] = (short)f2bf(e[r] * inv);
  *(short8*)(base + tid * 8) = o8;
}

// ---------------- launcher ----------------
extern "C" void kernel_launch(void* const* d_in, const int* in_sizes, int n_in,
                              void* d_out, int out_size, void* d_ws, size_t ws_size,
                              hipStream_t stream) {
  const float* tensor = (const float*)d_in[0];
  const void* mask = d_in[1];
  const float* lnw = (const float*)d_in[2];
  const float* lnb = (const float*)d_in[3];
  const float* wk = (const float*)d_in[4];
  const float* bk = (const float*)d_in[5];
  float* out = (float*)d_out;

  // ws layout (bytes):
  //   0     : Wk_t bf16 [1024][1024]                    (2 MB)
  //   2 MB  : qkv_n bf16 [8192][1024]                   (16 MB)
  //   18 MB : qkv_t bf16 [4][1024][2048]                (16 MB)
  //   34 MB : x bf16 (dead after gemm0) / scores bf16 [4][2048][2048] (32 MB)
  //   66 MB : mask-dtype flag                            (4 B)
  char* ws = (char*)d_ws;
  bf16* wkt = (bf16*)(ws);
  bf16* qkvn = (bf16*)(ws + (2ll << 20));
  bf16* qkvt = (bf16*)(ws + (18ll << 20));
  bf16* xbf = (bf16*)(ws + (34ll << 20));
  unsigned short* scores = (unsigned short*)(ws + (34ll << 20));
  int* flag = (int*)(ws + (66ll << 20));

  detect_mask_kernel<<<1, 256, 0, stream>>>((const unsigned int*)mask, flag);
  pe_ln_kernel<<<8192, 256, 0, stream>>>(tensor, lnw, lnb, xbf);
  wk_to_bf16t_kernel<<<dim3(32, 32), 256, 0, stream>>>(wk, wkt);

  // qkv = x @ Wk + bk   (M=8192, N=1024, K=1024); dual-write row-major + transposed
  gemm_bt_kernel<0><<<dim3(8, 64, 1), 256, 0, stream>>>(
      xbf, 1024, 0, wkt, 1024, 0, 1024,
      (void*)qkvn, 1024, 0, bk, qkvt);

  // scores = qkv @ qkv^T / 32, bf16 (mask applied in softmax)
  gemm_bt_kernel<1><<<dim3(16, 16, 4), 256, 0, stream>>>(
      qkvn, 1024, 2048ll * 1024,
      qkvn, 1024, 2048ll * 1024, 1024,
      (void*)scores, 2048, 2048ll * 2048, nullptr, nullptr);

  // fused mask-fill(1e-9) + softmax rows, in-place bf16 -> bf16
  softmax_kernel<<<8192, 256, 0, stream>>>(scores, mask, flag);

  // out = weights @ qkv  (all 4 batches: M=2048, N=1024, K=2048)
  gemm_bt_kernel<2><<<dim3(8, 16, 4), 256, 0, stream>>>(
      (const bf16*)scores, 2048, 2048ll * 2048,
      qkvt, 2048, 1024ll * 2048, 2048,
      (void*)out, 1024, 2048ll * 1024,
      nullptr, nullptr);
}

// Round 5
// 155.917 us; speedup vs baseline: 1.5176x; 1.0709x over previous
//
#include <hip/hip_runtime.h>
#include <hip/hip_bf16.h>

#define S_LEN 2048
#define D_DIM 1024

typedef float f32x4 __attribute__((ext_vector_type(4)));
typedef short short8 __attribute__((ext_vector_type(8)));
typedef unsigned short us4 __attribute__((ext_vector_type(4)));
typedef unsigned int u32x4 __attribute__((ext_vector_type(4)));

using bf16 = __hip_bfloat16;

#define GLOBAL_AS(p) ((const __attribute__((address_space(1))) void*)(p))
#define LDS_AS(p) ((__attribute__((address_space(3))) void*)(p))

static __device__ __forceinline__ unsigned short f2bf(float f) {
  bf16 h = __float2bfloat16(f);
  return *reinterpret_cast<unsigned short*>(&h);
}
static __device__ __forceinline__ float bf2f(unsigned short u) {
  unsigned int w = ((unsigned int)u) << 16;
  return __builtin_bit_cast(float, w);
}

// ---------------- mask dtype probe: 0=int32, 1=uint8, 2=float32 ----------------
__global__ void detect_mask_kernel(const unsigned int* __restrict__ m, int* __restrict__ flag) {
  __shared__ int sh;
  if (threadIdx.x == 0) sh = 0;
  __syncthreads();
  int f = 0;
  for (int i = threadIdx.x; i < 4096; i += 256) {
    unsigned int w = m[i];
    if (w == 0x3f800000u) f |= 2;
    if (w & 0xFFFFFF00u) f |= 1;
  }
  if (f) atomicOr(&sh, f);
  __syncthreads();
  if (threadIdx.x == 0) *flag = (sh & 2) ? 2 : ((sh & 1) ? 1 : 0);
}

// ---------------- fused positional-encoding + LayerNorm -> bf16 ----------------
__global__ __launch_bounds__(256) void pe_ln_kernel(
    const float* __restrict__ x, const float* __restrict__ lnw,
    const float* __restrict__ lnb, bf16* __restrict__ out) {
  const int row = blockIdx.x;
  const int s = row & (S_LEN - 1);
  const int tid = threadIdx.x;
  const float pos = (float)s;
  const float* base = x + (size_t)row * D_DIM;

  f32x4 v = *(const f32x4*)(base + tid * 4);
  float h[4];
#pragma unroll
  for (int r = 0; r < 4; ++r) {
    int d = tid * 4 + r;
    float dv = (float)d * (2.0f / 1024.0f);
    float freq = exp2f(dv * -13.287712379549449f);
    float pe = pos * freq;
    float pv = (d & 1) ? cosf(pe) : sinf(pe);
    h[r] = pv + v[r];
  }
  float ss = h[0] + h[1] + h[2] + h[3];
#pragma unroll
  for (int o = 32; o >= 1; o >>= 1) ss += __shfl_xor(ss, o);
  __shared__ float red[8];
  const int wave = tid >> 6, lane = tid & 63;
  if (lane == 0) red[wave] = ss;
  __syncthreads();
  const float mu = (red[0] + red[1] + red[2] + red[3]) * (1.0f / 1024.0f);
  float sq = 0.f;
#pragma unroll
  for (int r = 0; r < 4; ++r) { float d0 = h[r] - mu; sq += d0 * d0; }
#pragma unroll
  for (int o = 32; o >= 1; o >>= 1) sq += __shfl_xor(sq, o);
  if (lane == 0) red[4 + wave] = sq;
  __syncthreads();
  const float var = (red[4] + red[5] + red[6] + red[7]) * (1.0f / 1024.0f);
  const float inv = rsqrtf(var + 1e-5f);
  f32x4 wv = *(const f32x4*)(lnw + tid * 4);
  f32x4 bv = *(const f32x4*)(lnb + tid * 4);
  us4 o4;
#pragma unroll
  for (int r = 0; r < 4; ++r) o4[r] = f2bf((h[r] - mu) * inv * wv[r] + bv[r]);
  *(us4*)((unsigned short*)out + (size_t)row * D_DIM + tid * 4) = o4;
}

// ---------------- Wk fp32 [K][N] -> bf16 transposed [N][K] ----------------
__global__ __launch_bounds__(256) void wk_to_bf16t_kernel(const float* __restrict__ wk,
                                                          bf16* __restrict__ wt) {
  __shared__ float t[32][33];
  const int n0 = blockIdx.x * 32, k0 = blockIdx.y * 32;
  const int tx = threadIdx.x & 31, ty = threadIdx.x >> 5;
#pragma unroll
  for (int i = 0; i < 32; i += 8)
    t[ty + i][tx] = wk[(size_t)(k0 + ty + i) * 1024 + n0 + tx];
  __syncthreads();
#pragma unroll
  for (int i = 0; i < 32; i += 8)
    wt[(size_t)(n0 + ty + i) * 1024 + k0 + tx] = __float2bfloat16(t[tx][ty + i]);
}

// ---------------- bf16 GEMM, C = A[M][K] * B_t[N][K]^T ----------------
// 128x128 tile, BK=32, global_load_lds(16B), counted-vmcnt 3-deep pipeline,
// both-sides XOR swizzle on LDS 16B slots.
// EPI 0: + bias, write bf16 C row-major AND bf16 transposed copy
// EPI 1: * 1/32, write bf16; SYMMETRIC: triangular block grid + mirrored tile write
// EPI 2: plain fp32 write
template <int EPI>
__global__ __launch_bounds__(256) void gemm_bt_kernel(
    const bf16* __restrict__ A, int lda, long long A_bs,
    const bf16* __restrict__ B, int ldb, long long B_bs,
    int K,
    void* __restrict__ C, int ldc, long long C_bs,
    const float* __restrict__ bias, bf16* __restrict__ qkv_t) {
  __shared__ bf16 sbuf[3][2][128 * 32];  // [3-deep][A|B][128 rows * 32 k] = 48 KB

  const int tid = threadIdx.x;
  const int wave = tid >> 6, lane = tid & 63;
  const int wr = wave >> 1, wc = wave & 1;

  int bx, by, z;
  if constexpr (EPI == 1) {
    // triangular grid: 4 batches x 136 upper-triangle blocks of a 16x16 grid
    int lin = blockIdx.x;
    lin = (lin & 7) * 68 + (lin >> 3);  // bijective XCD swizzle (544 % 8 == 0)
    z = lin / 136;
    int t = lin - z * 136;
    int off = 0;
    by = 0;
#pragma unroll 1
    for (int r = 0; r < 16; ++r) {
      int cnt = 16 - r;
      if (t < off + cnt) { by = r; break; }
      off += cnt;
    }
    bx = by + (t - off);
  } else {
    // bijective XCD-aware swizzle of the flattened block id (grids % 8 == 0)
    const int gx = gridDim.x, gy = gridDim.y;
    const int nwg = gx * gy * gridDim.z;
    int lin = (blockIdx.z * gy + blockIdx.y) * gx + blockIdx.x;
    lin = (lin & 7) * (nwg >> 3) + (lin >> 3);
    bx = lin % gx;
    by = (lin / gx) % gy;
    z = lin / (gx * gy);
  }

  const int m0 = by * 128;
  const int n0 = bx * 128;

  const bf16* Ab = A + (size_t)z * A_bs;
  const bf16* Bb = B + (size_t)z * B_bs;

  // staging: wave covers 16 rows x 32 k (1 KB) per inst; lane L -> row base+L/4,
  // 16B slot = (L&3) XOR ((row>>1)&3)   [source pre-swizzle, LDS dest linear]
  const int grow = lane >> 2;
  const int scol = ((lane & 3) ^ ((lane >> 3) & 3)) * 8;

  const size_t a_off0 = (size_t)(m0 + wave * 16 + grow) * lda + scol;
  const size_t a_off1 = a_off0 + (size_t)64 * lda;
  const size_t b_off0 = (size_t)(n0 + wave * 16 + grow) * ldb + scol;
  const size_t b_off1 = b_off0 + (size_t)64 * ldb;
  const int ldsw = wave * 512;

#define STAGE(bufi, kk)                                                          \
  do {                                                                           \
    bf16* sa_ = &sbuf[bufi][0][0];                                               \
    bf16* sb_ = &sbuf[bufi][1][0];                                               \
    __builtin_amdgcn_global_load_lds(GLOBAL_AS(Ab + a_off0 + (kk)),              \
                                     LDS_AS(sa_ + ldsw), 16, 0, 0);              \
    __builtin_amdgcn_global_load_lds(GLOBAL_AS(Ab + a_off1 + (kk)),              \
                                     LDS_AS(sa_ + 2048 + ldsw), 16, 0, 0);       \
    __builtin_amdgcn_global_load_lds(GLOBAL_AS(Bb + b_off0 + (kk)),              \
                                     LDS_AS(sb_ + ldsw), 16, 0, 0);              \
    __builtin_amdgcn_global_load_lds(GLOBAL_AS(Bb + b_off1 + (kk)),              \
                                     LDS_AS(sb_ + 2048 + ldsw), 16, 0, 0);       \
  } while (0)

  f32x4 acc[4][4];
#pragma unroll
  for (int i = 0; i < 4; ++i)
#pragma unroll
    for (int j = 0; j < 4; ++j) acc[i][j] = (f32x4)(0.0f);

  // fragment-read geometry (same XOR on the 16B slot index)
  const int lrow = lane & 15;
  const int slot0 = lane >> 4;
  const int rsw = (lrow >> 1) & 3;
  const int rdA = (wr * 64 + lrow) * 32 + ((slot0 ^ rsw) * 8);
  const int rdB = (wc * 64 + lrow) * 32 + ((slot0 ^ rsw) * 8);

  const int NT = K >> 5;
  STAGE(0, 0);
  STAGE(1, 32);
  STAGE(2, 64);
  int cb = 0;
  for (int kt = 0; kt < NT; ++kt) {
    // tiles kt..kt+2 may be in flight; ensure tile kt's 4 loads landed,
    // keep up to 8 (two tiles) outstanding — never drain to 0 mid-loop
    const int ahead = NT - 1 - kt;
    if (ahead >= 2)      asm volatile("s_waitcnt vmcnt(8)" ::: "memory");
    else if (ahead == 1) asm volatile("s_waitcnt vmcnt(4)" ::: "memory");
    else                 asm volatile("s_waitcnt vmcnt(0)" ::: "memory");
    __builtin_amdgcn_s_barrier();
    const bf16* sa = &sbuf[cb][0][0];
    const bf16* sb = &sbuf[cb][1][0];
    short8 af[4], bfr[4];
#pragma unroll
    for (int i = 0; i < 4; ++i) {
      af[i] = *(const short8*)(sa + rdA + i * 512);
      bfr[i] = *(const short8*)(sb + rdB + i * 512);
    }
#pragma unroll
    for (int i = 0; i < 4; ++i)
#pragma unroll
      for (int j = 0; j < 4; ++j)
        acc[i][j] = __builtin_amdgcn_mfma_f32_16x16x32_bf16(af[i], bfr[j], acc[i][j], 0, 0, 0);
    if (kt + 3 < NT) {
      __builtin_amdgcn_s_barrier();  // all waves' reads of buf[cb] done -> overwrite ok
      STAGE(cb, (size_t)(kt + 3) * 32);
    }
    cb = (cb == 2) ? 0 : cb + 1;
  }
#undef STAGE

  // epilogue: C/D layout col = lane&15, row = (lane>>4)*4 + reg  [measured m89]
  const int r0 = (lane >> 4) * 4;
#pragma unroll
  for (int i = 0; i < 4; ++i) {
    const int rowl = m0 + wr * 64 + i * 16 + r0;
#pragma unroll
    for (int j = 0; j < 4; ++j) {
      const int col = n0 + wc * 64 + j * 16 + lrow;
      if (EPI == 0) {
        const float bv = bias[col];
        us4 pack;
#pragma unroll
        for (int r = 0; r < 4; ++r) {
          unsigned short hb = f2bf(acc[i][j][r] + bv);
          ((unsigned short*)C)[(size_t)(rowl + r) * ldc + col] = hb;
          pack[r] = hb;
        }
        const int bb = rowl >> 11, s = rowl & 2047;
        *(us4*)((unsigned short*)qkv_t + (size_t)bb * (1024ll * 2048) +
                (size_t)col * 2048 + s) = pack;
      } else if (EPI == 1) {
        unsigned short* Cb = (unsigned short*)C + (size_t)z * C_bs;
        us4 pack;
#pragma unroll
        for (int r = 0; r < 4; ++r) {
          unsigned short hb = f2bf(acc[i][j][r] * 0.03125f);
          Cb[(size_t)(rowl + r) * ldc + col] = hb;
          pack[r] = hb;
        }
        if (bx != by)  // mirror tile: scores are symmetric, write C[col][rowl..rowl+3]
          *(us4*)(Cb + (size_t)col * ldc + rowl) = pack;
      } else {
#pragma unroll
        for (int r = 0; r < 4; ++r)
          ((float*)C + (size_t)z * C_bs)[(size_t)(rowl + r) * ldc + col] = acc[i][j][r];
      }
    }
  }
}

// ---------------- fused mask + in-place row softmax on bf16 scores ----------------
__global__ __launch_bounds__(256) void softmax_kernel(
    unsigned short* __restrict__ scores, const void* __restrict__ mask,
    const int* __restrict__ flagp) {
  const int row = blockIdx.x;  // 8192 rows = b*2048 + q
  const int fmode = *flagp;
  unsigned short* base = scores + (size_t)row * 2048;
  const int tid = threadIdx.x;
  const int wave = tid >> 6, lane = tid & 63;

  short8 v = *(const short8*)(base + tid * 8);
  float x[8];
#pragma unroll
  for (int r = 0; r < 8; ++r) x[r] = bf2f((unsigned short)v[r]);

  const size_t mofs = (size_t)row * 2048 + tid * 8;
  if (fmode == 0) {
    const unsigned int* mp = (const unsigned int*)mask + mofs;
    u32x4 m0 = *(const u32x4*)mp;
    u32x4 m1 = *(const u32x4*)(mp + 4);
#pragma unroll
    for (int r = 0; r < 4; ++r) { if (m0[r]) x[r] = 1e-9f; }
#pragma unroll
    for (int r = 0; r < 4; ++r) { if (m1[r]) x[4 + r] = 1e-9f; }
  } else if (fmode == 1) {
    const unsigned char* mp = (const unsigned char*)mask + mofs;
    us4 mb = *(const us4*)mp;  // 8 bytes
#pragma unroll
    for (int r = 0; r < 4; ++r) {
      if (mb[r] & 0x00FF) x[2 * r] = 1e-9f;
      if (mb[r] & 0xFF00) x[2 * r + 1] = 1e-9f;
    }
  } else {
    const float* mp = (const float*)mask + mofs;
    f32x4 m0 = *(const f32x4*)mp;
    f32x4 m1 = *(const f32x4*)(mp + 4);
#pragma unroll
    for (int r = 0; r < 4; ++r) { if (m0[r] != 0.0f) x[r] = 1e-9f; }
#pragma unroll
    for (int r = 0; r < 4; ++r) { if (m1[r] != 0.0f) x[4 + r] = 1e-9f; }
  }

  float m = x[0];
#pragma unroll
  for (int r = 1; r < 8; ++r) m = fmaxf(m, x[r]);
#pragma unroll
  for (int o = 32; o >= 1; o >>= 1) m = fmaxf(m, __shfl_xor(m, o));
  __shared__ float red[8];
  if (lane == 0) red[wave] = m;
  __syncthreads();
  m = fmaxf(fmaxf(red[0], red[1]), fmaxf(red[2], red[3]));
  float e[8], sum = 0.f;
#pragma unroll
  for (int r = 0; r < 8; ++r) { e[r] = expf(x[r] - m); sum += e[r]; }
#pragma unroll
  for (int o = 32; o >= 1; o >>= 1) sum += __shfl_xor(sum, o);
  if (lane == 0) red[4 + wave] = sum;
  __syncthreads();
  const float inv = 1.0f / (red[4] + red[5] + red[6] + red[7]);
  short8 o8;
#pragma unroll
  for (int r = 0; r < 8; ++r) o8[r] = (short)f2bf(e[r] * inv);
  *(short8*)(base + tid * 8) = o8;
}

// ---------------- launcher ----------------
extern "C" void kernel_launch(void* const* d_in, const int* in_sizes, int n_in,
                              void* d_out, int out_size, void* d_ws, size_t ws_size,
                              hipStream_t stream) {
  const float* tensor = (const float*)d_in[0];
  const void* mask = d_in[1];
  const float* lnw = (const float*)d_in[2];
  const float* lnb = (const float*)d_in[3];
  const float* wk = (const float*)d_in[4];
  const float* bk = (const float*)d_in[5];
  float* out = (float*)d_out;

  // ws layout (bytes):
  //   0     : Wk_t bf16 [1024][1024]                    (2 MB)
  //   2 MB  : qkv_n bf16 [8192][1024]                   (16 MB)
  //   18 MB : qkv_t bf16 [4][1024][2048]                (16 MB)
  //   34 MB : x bf16 (dead after gemm0) / scores bf16 [4][2048][2048] (32 MB)
  //   66 MB : mask-dtype flag                            (4 B)
  char* ws = (char*)d_ws;
  bf16* wkt = (bf16*)(ws);
  bf16* qkvn = (bf16*)(ws + (2ll << 20));
  bf16* qkvt = (bf16*)(ws + (18ll << 20));
  bf16* xbf = (bf16*)(ws + (34ll << 20));
  unsigned short* scores = (unsigned short*)(ws + (34ll << 20));
  int* flag = (int*)(ws + (66ll << 20));

  detect_mask_kernel<<<1, 256, 0, stream>>>((const unsigned int*)mask, flag);
  pe_ln_kernel<<<8192, 256, 0, stream>>>(tensor, lnw, lnb, xbf);
  wk_to_bf16t_kernel<<<dim3(32, 32), 256, 0, stream>>>(wk, wkt);

  // qkv = x @ Wk + bk   (M=8192, N=1024, K=1024); dual-write row-major + transposed
  gemm_bt_kernel<0><<<dim3(8, 64, 1), 256, 0, stream>>>(
      xbf, 1024, 0, wkt, 1024, 0, 1024,
      (void*)qkvn, 1024, 0, bk, qkvt);

  // scores = qkv @ qkv^T / 32, bf16, SYMMETRIC: 136 upper blocks x 4 batches
  gemm_bt_kernel<1><<<dim3(544, 1, 1), 256, 0, stream>>>(
      qkvn, 1024, 2048ll * 1024,
      qkvn, 1024, 2048ll * 1024, 1024,
      (void*)scores, 2048, 2048ll * 2048, nullptr, nullptr);

  // fused mask-fill(1e-9) + softmax rows, in-place bf16 -> bf16
  softmax_kernel<<<8192, 256, 0, stream>>>(scores, mask, flag);

  // out = weights @ qkv  (all 4 batches: M=2048, N=1024, K=2048)
  gemm_bt_kernel<2><<<dim3(8, 16, 4), 256, 0, stream>>>(
      (const bf16*)scores, 2048, 2048ll * 2048,
      qkvt, 2048, 1024ll * 2048, 2048,
      (void*)out, 1024, 2048ll * 1024,
      nullptr, nullptr);
}

// Round 6
// 152.595 us; speedup vs baseline: 1.5507x; 1.0218x over previous
//
#include <hip/hip_runtime.h>
#include <hip/hip_bf16.h>

#define S_LEN 2048
#define D_DIM 1024

typedef float f32x4 __attribute__((ext_vector_type(4)));
typedef short short8 __attribute__((ext_vector_type(8)));
typedef unsigned short us4 __attribute__((ext_vector_type(4)));
typedef unsigned short us8 __attribute__((ext_vector_type(8)));
typedef unsigned int u32x4 __attribute__((ext_vector_type(4)));

using bf16 = __hip_bfloat16;

#define GLOBAL_AS(p) ((const __attribute__((address_space(1))) void*)(p))
#define LDS_AS(p) ((__attribute__((address_space(3))) void*)(p))

static __device__ __forceinline__ unsigned short f2bf(float f) {
  bf16 h = __float2bfloat16(f);
  return *reinterpret_cast<unsigned short*>(&h);
}
static __device__ __forceinline__ float bf2f(unsigned short u) {
  unsigned int w = ((unsigned int)u) << 16;
  return __builtin_bit_cast(float, w);
}

// ---------------- mask dtype probe: 0=int32, 1=uint8, 2=float32 ----------------
__global__ void detect_mask_kernel(const unsigned int* __restrict__ m, int* __restrict__ flag) {
  __shared__ int sh;
  if (threadIdx.x == 0) sh = 0;
  __syncthreads();
  int f = 0;
  for (int i = threadIdx.x; i < 4096; i += 256) {
    unsigned int w = m[i];
    if (w == 0x3f800000u) f |= 2;
    if (w & 0xFFFFFF00u) f |= 1;
  }
  if (f) atomicOr(&sh, f);
  __syncthreads();
  if (threadIdx.x == 0) *flag = (sh & 2) ? 2 : ((sh & 1) ? 1 : 0);
}

// ---------------- fused positional-encoding + LayerNorm -> bf16 ----------------
__global__ __launch_bounds__(256) void pe_ln_kernel(
    const float* __restrict__ x, const float* __restrict__ lnw,
    const float* __restrict__ lnb, bf16* __restrict__ out) {
  const int row = blockIdx.x;
  const int s = row & (S_LEN - 1);
  const int tid = threadIdx.x;
  const float pos = (float)s;
  const float* base = x + (size_t)row * D_DIM;

  f32x4 v = *(const f32x4*)(base + tid * 4);
  float h[4];
#pragma unroll
  for (int r = 0; r < 4; ++r) {
    int d = tid * 4 + r;
    float dv = (float)d * (2.0f / 1024.0f);
    float freq = exp2f(dv * -13.287712379549449f);
    float pe = pos * freq;
    float pv = (d & 1) ? __cosf(pe) : __sinf(pe);  // hw v_sin/v_cos, bf16-accurate
    h[r] = pv + v[r];
  }
  float ss = h[0] + h[1] + h[2] + h[3];
#pragma unroll
  for (int o = 32; o >= 1; o >>= 1) ss += __shfl_xor(ss, o);
  __shared__ float red[8];
  const int wave = tid >> 6, lane = tid & 63;
  if (lane == 0) red[wave] = ss;
  __syncthreads();
  const float mu = (red[0] + red[1] + red[2] + red[3]) * (1.0f / 1024.0f);
  float sq = 0.f;
#pragma unroll
  for (int r = 0; r < 4; ++r) { float d0 = h[r] - mu; sq += d0 * d0; }
#pragma unroll
  for (int o = 32; o >= 1; o >>= 1) sq += __shfl_xor(sq, o);
  if (lane == 0) red[4 + wave] = sq;
  __syncthreads();
  const float var = (red[4] + red[5] + red[6] + red[7]) * (1.0f / 1024.0f);
  const float inv = rsqrtf(var + 1e-5f);
  f32x4 wv = *(const f32x4*)(lnw + tid * 4);
  f32x4 bv = *(const f32x4*)(lnb + tid * 4);
  us4 o4;
#pragma unroll
  for (int r = 0; r < 4; ++r) o4[r] = f2bf((h[r] - mu) * inv * wv[r] + bv[r]);
  *(us4*)((unsigned short*)out + (size_t)row * D_DIM + tid * 4) = o4;
}

// ---------------- Wk fp32 [K][N] -> bf16 transposed [N][K] ----------------
__global__ __launch_bounds__(256) void wk_to_bf16t_kernel(const float* __restrict__ wk,
                                                          bf16* __restrict__ wt) {
  __shared__ float t[32][33];
  const int n0 = blockIdx.x * 32, k0 = blockIdx.y * 32;
  const int tx = threadIdx.x & 31, ty = threadIdx.x >> 5;
#pragma unroll
  for (int i = 0; i < 32; i += 8)
    t[ty + i][tx] = wk[(size_t)(k0 + ty + i) * 1024 + n0 + tx];
  __syncthreads();
#pragma unroll
  for (int i = 0; i < 32; i += 8)
    wt[(size_t)(n0 + ty + i) * 1024 + k0 + tx] = __float2bfloat16(t[tx][ty + i]);
}

// ---------------- bf16 GEMM, C = A[M][K] * B_t[N][K]^T ----------------
// 128x128 tile, BK=32, global_load_lds(16B), 3-buffer stage-2-ahead pipeline,
// ONE barrier + counted vmcnt per K-step, both-sides XOR swizzle on 16B slots.
// EPI 0: + bias, write bf16 C row-major AND bf16 transposed copy
// EPI 1: * 1/32, write bf16; SYMMETRIC: triangular grid + LDS-transposed mirror
// EPI 2: plain fp32 write
template <int EPI>
__global__ __launch_bounds__(256) void gemm_bt_kernel(
    const bf16* __restrict__ A, int lda, long long A_bs,
    const bf16* __restrict__ B, int ldb, long long B_bs,
    int K,
    void* __restrict__ C, int ldc, long long C_bs,
    const float* __restrict__ bias, bf16* __restrict__ qkv_t) {
  __shared__ bf16 sbuf[3][2][128 * 32];  // [3-deep][A|B][128 rows * 32 k] = 48 KB

  const int tid = threadIdx.x;
  const int wave = tid >> 6, lane = tid & 63;
  const int wr = wave >> 1, wc = wave & 1;

  int bx, by, z;
  if constexpr (EPI == 1) {
    // triangular grid: 4 batches x 136 upper-triangle blocks of a 16x16 grid
    int lin = blockIdx.x;
    lin = (lin & 7) * 68 + (lin >> 3);  // bijective XCD swizzle (544 % 8 == 0)
    z = lin / 136;
    int t = lin - z * 136;
    int off = 0;
    by = 0;
#pragma unroll 1
    for (int r = 0; r < 16; ++r) {
      int cnt = 16 - r;
      if (t < off + cnt) { by = r; break; }
      off += cnt;
    }
    bx = by + (t - off);
  } else {
    // bijective XCD-aware swizzle of the flattened block id (grids % 8 == 0)
    const int gx = gridDim.x, gy = gridDim.y;
    const int nwg = gx * gy * gridDim.z;
    int lin = (blockIdx.z * gy + blockIdx.y) * gx + blockIdx.x;
    lin = (lin & 7) * (nwg >> 3) + (lin >> 3);
    bx = lin % gx;
    by = (lin / gx) % gy;
    z = lin / (gx * gy);
  }

  const int m0 = by * 128;
  const int n0 = bx * 128;

  const bf16* Ab = A + (size_t)z * A_bs;
  const bf16* Bb = B + (size_t)z * B_bs;

  // staging: wave covers 16 rows x 32 k (1 KB) per inst; lane L -> row base+L/4,
  // 16B slot = (L&3) XOR ((row>>1)&3)   [source pre-swizzle, LDS dest linear]
  const int grow = lane >> 2;
  const int scol = ((lane & 3) ^ ((lane >> 3) & 3)) * 8;

  const size_t a_off0 = (size_t)(m0 + wave * 16 + grow) * lda + scol;
  const size_t a_off1 = a_off0 + (size_t)64 * lda;
  const size_t b_off0 = (size_t)(n0 + wave * 16 + grow) * ldb + scol;
  const size_t b_off1 = b_off0 + (size_t)64 * ldb;
  const int ldsw = wave * 512;

#define STAGE(bufi, kk)                                                          \
  do {                                                                           \
    bf16* sa_ = &sbuf[bufi][0][0];                                               \
    bf16* sb_ = &sbuf[bufi][1][0];                                               \
    __builtin_amdgcn_global_load_lds(GLOBAL_AS(Ab + a_off0 + (kk)),              \
                                     LDS_AS(sa_ + ldsw), 16, 0, 0);              \
    __builtin_amdgcn_global_load_lds(GLOBAL_AS(Ab + a_off1 + (kk)),              \
                                     LDS_AS(sa_ + 2048 + ldsw), 16, 0, 0);       \
    __builtin_amdgcn_global_load_lds(GLOBAL_AS(Bb + b_off0 + (kk)),              \
                                     LDS_AS(sb_ + ldsw), 16, 0, 0);              \
    __builtin_amdgcn_global_load_lds(GLOBAL_AS(Bb + b_off1 + (kk)),              \
                                     LDS_AS(sb_ + 2048 + ldsw), 16, 0, 0);       \
  } while (0)

  f32x4 acc[4][4];
#pragma unroll
  for (int i = 0; i < 4; ++i)
#pragma unroll
    for (int j = 0; j < 4; ++j) acc[i][j] = (f32x4)(0.0f);

  // fragment-read geometry (same XOR on the 16B slot index)
  const int lrow = lane & 15;
  const int slot0 = lane >> 4;
  const int rsw = (lrow >> 1) & 3;
  const int rdA = (wr * 64 + lrow) * 32 + ((slot0 ^ rsw) * 8);
  const int rdB = (wc * 64 + lrow) * 32 + ((slot0 ^ rsw) * 8);

  const int NT = K >> 5;
  STAGE(0, 0);
  STAGE(1, 32);
  int cb = 0;
  for (int kt = 0; kt < NT; ++kt) {
    // tile kt landed; tile kt+1's 4 loads stay in flight (never drain mid-loop)
    if (kt < NT - 1) asm volatile("s_waitcnt vmcnt(4)" ::: "memory");
    else             asm volatile("s_waitcnt vmcnt(0)" ::: "memory");
    __builtin_amdgcn_s_barrier();
    // stage tile kt+2 into buf[(kt+2)%3] == buf[(kt-1)%3]: all waves finished
    // reading it in iter kt-1 (their ds_reads complete before their MFMAs,
    // which precede this barrier) -> race-free with ONE barrier per step.
    if (kt + 2 < NT) {
      int sb2 = cb + 2; if (sb2 >= 3) sb2 -= 3;
      STAGE(sb2, (size_t)(kt + 2) * 32);
    }
    const bf16* sa = &sbuf[cb][0][0];
    const bf16* sb = &sbuf[cb][1][0];
    short8 af[4], bfr[4];
#pragma unroll
    for (int i = 0; i < 4; ++i) {
      af[i] = *(const short8*)(sa + rdA + i * 512);
      bfr[i] = *(const short8*)(sb + rdB + i * 512);
    }
#pragma unroll
    for (int i = 0; i < 4; ++i)
#pragma unroll
      for (int j = 0; j < 4; ++j)
        acc[i][j] = __builtin_amdgcn_mfma_f32_16x16x32_bf16(af[i], bfr[j], acc[i][j], 0, 0, 0);
    cb = (cb == 2) ? 0 : cb + 1;
  }
#undef STAGE

  // epilogue: C/D layout col = lane&15, row = (lane>>4)*4 + reg  [measured m89]
  const int r0 = (lane >> 4) * 4;
#pragma unroll
  for (int i = 0; i < 4; ++i) {
    const int rowl = m0 + wr * 64 + i * 16 + r0;
#pragma unroll
    for (int j = 0; j < 4; ++j) {
      const int col = n0 + wc * 64 + j * 16 + lrow;
      if (EPI == 0) {
        const float bv = bias[col];
        us4 pack;
#pragma unroll
        for (int r = 0; r < 4; ++r) {
          unsigned short hb = f2bf(acc[i][j][r] + bv);
          ((unsigned short*)C)[(size_t)(rowl + r) * ldc + col] = hb;
          pack[r] = hb;
        }
        const int bb = rowl >> 11, s = rowl & 2047;
        *(us4*)((unsigned short*)qkv_t + (size_t)bb * (1024ll * 2048) +
                (size_t)col * 2048 + s) = pack;
      } else if (EPI == 1) {
        unsigned short* Cb = (unsigned short*)C + (size_t)z * C_bs;
        us4 pack;
#pragma unroll
        for (int r = 0; r < 4; ++r) {
          unsigned short hb = f2bf(acc[i][j][r] * 0.03125f);
          Cb[(size_t)(rowl + r) * ldc + col] = hb;
          pack[r] = hb;
        }
        if (bx != by) {
          // stash transposed into LDS for a coalesced mirror write below
          unsigned short* tl = (unsigned short*)&sbuf[0][0][0];  // [128][132]
          const int lr = rowl - m0;  // local row 0..127
          const int lc = col - n0;   // local col 0..127
          *(us4*)(tl + (size_t)lc * 132 + lr) = pack;
        }
      } else {
#pragma unroll
        for (int r = 0; r < 4; ++r)
          ((float*)C + (size_t)z * C_bs)[(size_t)(rowl + r) * ldc + col] = acc[i][j][r];
      }
    }
  }

  if constexpr (EPI == 1) {
    // mirror tile write: scores symmetric -> C[n0+c][m0+r] = tile[r][c]
    const int gx2 = 0; (void)gx2;
    int lin2 = blockIdx.x;
    lin2 = (lin2 & 7) * 68 + (lin2 >> 3);
    // (bx,by,z already computed above; reuse)
    if (bx != by) {
      __syncthreads();  // transpose stash complete
      unsigned short* Cb = (unsigned short*)C + (size_t)z * C_bs;
      const unsigned short* tl = (const unsigned short*)&sbuf[0][0][0];
      // 8 iterations: 256 threads x 16B cover 16 transposed rows each pass;
      // 16 lanes per row -> 256B contiguous global segments
      const int c_in = tid >> 4;          // 0..15
      const int r8 = (tid & 15) * 8;      // col chunk
#pragma unroll
      for (int it = 0; it < 8; ++it) {
        const int c = it * 16 + c_in;
        us8 vv = *(const us8*)(tl + (size_t)c * 132 + r8);
        *(us8*)(Cb + (size_t)(n0 + c) * ldc + m0 + r8) = vv;
      }
    }
  }
}

// ---------------- fused mask + in-place row softmax on bf16 scores ----------------
__global__ __launch_bounds__(256) void softmax_kernel(
    unsigned short* __restrict__ scores, const void* __restrict__ mask,
    const int* __restrict__ flagp) {
  const int row = blockIdx.x;  // 8192 rows = b*2048 + q
  const int fmode = *flagp;
  unsigned short* base = scores + (size_t)row * 2048;
  const int tid = threadIdx.x;
  const int wave = tid >> 6, lane = tid & 63;

  short8 v = *(const short8*)(base + tid * 8);
  float x[8];
#pragma unroll
  for (int r = 0; r < 8; ++r) x[r] = bf2f((unsigned short)v[r]);

  const size_t mofs = (size_t)row * 2048 + tid * 8;
  if (fmode == 0) {
    const unsigned int* mp = (const unsigned int*)mask + mofs;
    u32x4 m0 = *(const u32x4*)mp;
    u32x4 m1 = *(const u32x4*)(mp + 4);
#pragma unroll
    for (int r = 0; r < 4; ++r) { if (m0[r]) x[r] = 1e-9f; }
#pragma unroll
    for (int r = 0; r < 4; ++r) { if (m1[r]) x[4 + r] = 1e-9f; }
  } else if (fmode == 1) {
    const unsigned char* mp = (const unsigned char*)mask + mofs;
    us4 mb = *(const us4*)mp;  // 8 bytes
#pragma unroll
    for (int r = 0; r < 4; ++r) {
      if (mb[r] & 0x00FF) x[2 * r] = 1e-9f;
      if (mb[r] & 0xFF00) x[2 * r + 1] = 1e-9f;
    }
  } else {
    const float* mp = (const float*)mask + mofs;
    f32x4 m0 = *(const f32x4*)mp;
    f32x4 m1 = *(const f32x4*)(mp + 4);
#pragma unroll
    for (int r = 0; r < 4; ++r) { if (m0[r] != 0.0f) x[r] = 1e-9f; }
#pragma unroll
    for (int r = 0; r < 4; ++r) { if (m1[r] != 0.0f) x[4 + r] = 1e-9f; }
  }

  float m = x[0];
#pragma unroll
  for (int r = 1; r < 8; ++r) m = fmaxf(m, x[r]);
#pragma unroll
  for (int o = 32; o >= 1; o >>= 1) m = fmaxf(m, __shfl_xor(m, o));
  __shared__ float red[8];
  if (lane == 0) red[wave] = m;
  __syncthreads();
  m = fmaxf(fmaxf(red[0], red[1]), fmaxf(red[2], red[3]));
  float e[8], sum = 0.f;
#pragma unroll
  for (int r = 0; r < 8; ++r) { e[r] = expf(x[r] - m); sum += e[r]; }
#pragma unroll
  for (int o = 32; o >= 1; o >>= 1) sum += __shfl_xor(sum, o);
  if (lane == 0) red[4 + wave] = sum;
  __syncthreads();
  const float inv = 1.0f / (red[4] + red[5] + red[6] + red[7]);
  short8 o8;
#pragma unroll
  for (int r = 0; r < 8; ++r) o8[r] = (short)f2bf(e[r] * inv);
  *(short8*)(base + tid * 8) = o8;
}

// ---------------- launcher ----------------
extern "C" void kernel_launch(void* const* d_in, const int* in_sizes, int n_in,
                              void* d_out, int out_size, void* d_ws, size_t ws_size,
                              hipStream_t stream) {
  const float* tensor = (const float*)d_in[0];
  const void* mask = d_in[1];
  const float* lnw = (const float*)d_in[2];
  const float* lnb = (const float*)d_in[3];
  const float* wk = (const float*)d_in[4];
  const float* bk = (const float*)d_in[5];
  float* out = (float*)d_out;

  // ws layout (bytes):
  //   0     : Wk_t bf16 [1024][1024]                    (2 MB)
  //   2 MB  : qkv_n bf16 [8192][1024]                   (16 MB)
  //   18 MB : qkv_t bf16 [4][1024][2048]                (16 MB)
  //   34 MB : x bf16 (dead after gemm0) / scores bf16 [4][2048][2048] (32 MB)
  //   66 MB : mask-dtype flag                            (4 B)
  char* ws = (char*)d_ws;
  bf16* wkt = (bf16*)(ws);
  bf16* qkvn = (bf16*)(ws + (2ll << 20));
  bf16* qkvt = (bf16*)(ws + (18ll << 20));
  bf16* xbf = (bf16*)(ws + (34ll << 20));
  unsigned short* scores = (unsigned short*)(ws + (34ll << 20));
  int* flag = (int*)(ws + (66ll << 20));

  detect_mask_kernel<<<1, 256, 0, stream>>>((const unsigned int*)mask, flag);
  pe_ln_kernel<<<8192, 256, 0, stream>>>(tensor, lnw, lnb, xbf);
  wk_to_bf16t_kernel<<<dim3(32, 32), 256, 0, stream>>>(wk, wkt);

  // qkv = x @ Wk + bk   (M=8192, N=1024, K=1024); dual-write row-major + transposed
  gemm_bt_kernel<0><<<dim3(8, 64, 1), 256, 0, stream>>>(
      xbf, 1024, 0, wkt, 1024, 0, 1024,
      (void*)qkvn, 1024, 0, bk, qkvt);

  // scores = qkv @ qkv^T / 32, bf16, SYMMETRIC: 136 upper blocks x 4 batches
  gemm_bt_kernel<1><<<dim3(544, 1, 1), 256, 0, stream>>>(
      qkvn, 1024, 2048ll * 1024,
      qkvn, 1024, 2048ll * 1024, 1024,
      (void*)scores, 2048, 2048ll * 2048, nullptr, nullptr);

  // fused mask-fill(1e-9) + softmax rows, in-place bf16 -> bf16
  softmax_kernel<<<8192, 256, 0, stream>>>(scores, mask, flag);

  // out = weights @ qkv  (all 4 batches: M=2048, N=1024, K=2048)
  gemm_bt_kernel<2><<<dim3(8, 16, 4), 256, 0, stream>>>(
      (const bf16*)scores, 2048, 2048ll * 2048,
      qkvt, 2048, 1024ll * 2048, 2048,
      (void*)out, 1024, 2048ll * 1024,
      nullptr, nullptr);
}